// Round 1
// baseline (1887.115 us; speedup 1.0000x reference)
//
#include <hip/hip_runtime.h>
#include <math.h>

// Problem: B=16, LQ=LKV=2048, DQ=DKV=H=512, all fp32.
// Reassociated (no softmax!):
//   G_b  = X_b^T X_b                       [512,512]  K=2048
//   s_b  = X_b^T 1                         [512]
//   E_b  = Wk G_b Wv^T + (Wk s)bv^T + bk(Wv s)^T + L bk bv^T   (= K^T V)
//   F_b  = Wq^T E_b / sqrt(H)              [512,512]
//   f0_b = bq^T E_b / sqrt(H)              [512]
//   ctx  = q_b F_b + 1 f0^T                [2048,512]

#define BM 64
#define BN 64
#define BKK 16

__global__ __launch_bounds__(256) void gemm_generic(
    const float* __restrict__ A, const float* __restrict__ B, float* __restrict__ C,
    int M, int N, int K,
    long sA_i, long sA_k, long sA_b,
    long sB_k, long sB_j, long sB_b,
    long sC_b,
    float alpha,
    const float* __restrict__ rowbias, long sRB_b)
{
    __shared__ float As[BKK][BM + 1];
    __shared__ float Bs[BKK][BN + 1];
    const int b  = blockIdx.z;
    const float* Ab = A + (long)b * sA_b;
    const float* Bb = B + (long)b * sB_b;
    const int i0 = blockIdx.y * BM;
    const int j0 = blockIdx.x * BN;
    const int tid = threadIdx.x;
    const int ty = tid >> 4;
    const int tx = tid & 15;

    float acc[4][4];
#pragma unroll
    for (int r = 0; r < 4; ++r)
#pragma unroll
        for (int c = 0; c < 4; ++c) acc[r][c] = 0.0f;

    for (int k0 = 0; k0 < K; k0 += BKK) {
        // ---- load A tile: As[k][i] = A(i0+i, k0+k) ----
        if (sA_i == 1) {
            // i-contiguous: map consecutive threads to consecutive i (coalesced)
#pragma unroll
            for (int e = 0; e < (BM * BKK) / 256; ++e) {
                int idx = tid + 256 * e;
                int i = idx & (BM - 1);
                int k = idx / BM;
                As[k][i] = Ab[(long)(i0 + i) + (long)(k0 + k) * sA_k];
            }
        } else {
            // k-contiguous: map consecutive threads to consecutive k
#pragma unroll
            for (int e = 0; e < (BM * BKK) / 256; ++e) {
                int idx = tid + 256 * e;
                int i = idx / BKK;
                int k = idx & (BKK - 1);
                As[k][i] = Ab[(long)(i0 + i) * sA_i + (long)(k0 + k) * sA_k];
            }
        }
        // ---- load B tile: Bs[k][j] = B(k0+k, j0+j) ----
        if (sB_j == 1) {
#pragma unroll
            for (int e = 0; e < (BN * BKK) / 256; ++e) {
                int idx = tid + 256 * e;
                int j = idx & (BN - 1);
                int k = idx / BN;
                Bs[k][j] = Bb[(long)(k0 + k) * sB_k + (long)(j0 + j)];
            }
        } else {
#pragma unroll
            for (int e = 0; e < (BN * BKK) / 256; ++e) {
                int idx = tid + 256 * e;
                int j = idx / BKK;
                int k = idx & (BKK - 1);
                Bs[k][j] = Bb[(long)(k0 + k) * sB_k + (long)(j0 + j) * sB_j];
            }
        }
        __syncthreads();

#pragma unroll
        for (int k = 0; k < BKK; ++k) {
            float a[4], bb[4];
#pragma unroll
            for (int r = 0; r < 4; ++r) a[r] = As[k][ty * 4 + r];
#pragma unroll
            for (int c = 0; c < 4; ++c) bb[c] = Bs[k][tx * 4 + c];
#pragma unroll
            for (int r = 0; r < 4; ++r)
#pragma unroll
                for (int c = 0; c < 4; ++c) acc[r][c] += a[r] * bb[c];
        }
        __syncthreads();
    }

    float* Cb = C + (long)b * sC_b;
#pragma unroll
    for (int r = 0; r < 4; ++r) {
        int i = i0 + ty * 4 + r;
#pragma unroll
        for (int c = 0; c < 4; ++c) {
            int j = j0 + tx * 4 + c;
            float v = acc[r][c] * alpha;
            if (rowbias) v += rowbias[(long)b * sRB_b + j];
            Cb[(long)i * N + j] = v;
        }
    }
}

// s_b[d] = sum_l X[b][l][d]
__global__ void colsum_kernel(const float* __restrict__ X, float* __restrict__ s,
                              int L, int D)
{
    int b = blockIdx.y;
    int d = blockIdx.x * blockDim.x + threadIdx.x;
    const float* Xb = X + (long)b * L * D;
    float acc = 0.0f;
    for (int l = 0; l < L; ++l) acc += Xb[(long)l * D + d];
    s[(long)b * D + d] = acc;
}

// y[b][j] = alpha * sum_i x[b][i] * A[b](i,j);  A(i,j) = A[i*sA_i + j*sA_j]
__global__ void matvec_kernel(const float* __restrict__ A, const float* __restrict__ x,
                              float* __restrict__ y, int NI, int NJ,
                              long sA_i, long sA_j, long sA_b,
                              long sx_b, long sy_b, float alpha)
{
    int b = blockIdx.y;
    int j = blockIdx.x * blockDim.x + threadIdx.x;
    const float* Ab = A + (long)b * sA_b;
    const float* xb = x + (long)b * sx_b;
    float acc = 0.0f;
    for (int i = 0; i < NI; ++i) acc += xb[i] * Ab[(long)i * sA_i + (long)j * sA_j];
    y[(long)b * sy_b + j] = acc * alpha;
}

// E[b] += u[b] bv^T + bk w[b]^T + L bk bv^T   (rank-1 bias fixups; zero here)
__global__ void rank1_kernel(float* __restrict__ E, const float* __restrict__ u,
                             const float* __restrict__ bv, const float* __restrict__ bk,
                             const float* __restrict__ w, float Lf, int H)
{
    int b = blockIdx.y;
    long idx = (long)blockIdx.x * blockDim.x + threadIdx.x;
    int h  = (int)(idx / H);
    int h2 = (int)(idx % H);
    E[(long)b * H * H + idx] +=
        u[(long)b * H + h] * bv[h2] + bk[h] * w[(long)b * H + h2] + Lf * bk[h] * bv[h2];
}

extern "C" void kernel_launch(void* const* d_in, const int* in_sizes, int n_in,
                              void* d_out, int out_size, void* d_ws, size_t ws_size,
                              hipStream_t stream)
{
    const float* q  = (const float*)d_in[0];
    const float* x  = (const float*)d_in[1];
    const float* Wq = (const float*)d_in[2];
    const float* bq = (const float*)d_in[3];
    const float* Wk = (const float*)d_in[4];
    const float* bk = (const float*)d_in[5];
    const float* Wv = (const float*)d_in[6];
    const float* bv = (const float*)d_in[7];
    float* out = (float*)d_out;

    const int Bn = 16, LQ = 2048, LKV = 2048, D = 512, H = 512;
    const float scale = 1.0f / sqrtf((float)H);

    float* ws = (float*)d_ws;
    float* G  = ws;                              // [16,512,512]; later reused as E
    float* A1 = ws + (size_t)Bn * D * H;         // [16,512,512]; later reused as F
    float* s  = ws + 2 * (size_t)Bn * D * H;     // [16,512]
    float* u  = s + (size_t)Bn * H;              // [16,512]
    float* w  = u + (size_t)Bn * H;              // [16,512]
    float* f0 = w + (size_t)Bn * H;              // [16,512]

    // 1) column sums of X
    colsum_kernel<<<dim3(D / 256, Bn), dim3(256), 0, stream>>>(x, s, LKV, D);

    // 2) G_b = X_b^T X_b   (M=512, N=512, K=2048)
    gemm_generic<<<dim3(D / BN, D / BM, Bn), dim3(256), 0, stream>>>(
        x, x, G, D, D, LKV,
        1L, (long)D, (long)LKV * D,
        (long)D, 1L, (long)LKV * D,
        (long)D * D, 1.0f, (const float*)nullptr, 0L);

    // 3) u_b = Wk s_b ; w_b = Wv s_b
    matvec_kernel<<<dim3(H / 256, Bn), dim3(256), 0, stream>>>(
        Wk, s, u, D, H, 1L, (long)D, 0L, (long)D, (long)H, 1.0f);
    matvec_kernel<<<dim3(H / 256, Bn), dim3(256), 0, stream>>>(
        Wv, s, w, D, H, 1L, (long)D, 0L, (long)D, (long)H, 1.0f);

    // 4) A1_b = Wk G_b   (M=H, N=D, K=D)
    gemm_generic<<<dim3(D / BN, H / BM, Bn), dim3(256), 0, stream>>>(
        Wk, G, A1, H, D, D,
        (long)D, 1L, 0L,
        (long)D, 1L, (long)D * D,
        (long)H * D, 1.0f, (const float*)nullptr, 0L);

    // 5) E_b = A1_b Wv^T  (M=H, N=H, K=D) -> overwrite G buffer
    float* E = G;
    gemm_generic<<<dim3(H / BN, H / BM, Bn), dim3(256), 0, stream>>>(
        A1, Wv, E, H, H, D,
        (long)D, 1L, (long)H * D,
        1L, (long)D, 0L,
        (long)H * H, 1.0f, (const float*)nullptr, 0L);

    // 6) rank-1 bias fixups on E
    rank1_kernel<<<dim3((H * H) / 256, Bn), dim3(256), 0, stream>>>(
        E, u, bv, bk, w, (float)LKV, H);

    // 7) f0_b = scale * bq^T E_b
    matvec_kernel<<<dim3(H / 256, Bn), dim3(256), 0, stream>>>(
        E, bq, f0, H, H, (long)H, 1L, (long)H * H, 0L, (long)H, scale);

    // 8) F_b = scale * Wq^T E_b  (M=D, N=H, K=H) -> overwrite A1 buffer
    float* F = A1;
    gemm_generic<<<dim3(H / BN, D / BM, Bn), dim3(256), 0, stream>>>(
        Wq, E, F, D, H, H,
        1L, (long)D, 0L,
        (long)H, 1L, (long)H * H,
        (long)D * H, scale, (const float*)nullptr, 0L);

    // 9) ctx_b = q_b F_b + 1 f0_b^T   (M=2048, N=512, K=512)
    gemm_generic<<<dim3(H / BN, LQ / BM, Bn), dim3(256), 0, stream>>>(
        q, F, out, LQ, H, D,
        (long)D, 1L, (long)LQ * D,
        (long)H, 1L, (long)D * H,
        (long)LQ * H, 1.0f, f0, (long)H);
}

// Round 2
// 453.247 us; speedup vs baseline: 4.1635x; 4.1635x over previous
//
#include <hip/hip_runtime.h>
#include <math.h>

// B=16, LQ=LKV=2048, D=H=512, fp32 in/out. No softmax -> reassociate:
//   G  = X^T X                   [512,512]  (K=2048)
//   E  = Wk G Wv^T (+rank-1 bias terms)  = K^T V
//   E2 = E^T = Wv A1^T,  A1 = Wk G
//   Ft = scale * E2 * Wq   (Ft[h'][d] = F[d][h'], F = scale*Wq^T E)
//   ctx= q * F + 1 f0^T,   f0 = scale * bq^T E
// All GEMMs as C = A * B^T with A[M,K], B[N,K] bf16 row-major (K-contig),
// using m97-structure MFMA (128x128 tile, 4 waves, global_load_lds w=16).

typedef unsigned short u16;
typedef __attribute__((ext_vector_type(8))) short bf16x8;
typedef __attribute__((ext_vector_type(4))) float f32x4;

__device__ __forceinline__ u16 f2bf(float f) {
    union { float f; unsigned u; } a; a.f = f;
    unsigned r = a.u + 0x7FFFu + ((a.u >> 16) & 1u);
    return (u16)(r >> 16);
}
__device__ __forceinline__ float bf2f(u16 h) {
    union { unsigned u; float f; } a; a.u = ((unsigned)h) << 16;
    return a.f;
}

// ---------------- MFMA GEMM: C[M,N] = alpha * A[M,K] B[N,K]^T (+rowbias[j]) ---
template<bool OUT_BF16>
__global__ __launch_bounds__(256) void gemm_bt(
    const u16* __restrict__ A, const u16* __restrict__ B, void* __restrict__ Cv,
    int M, int N, int K,
    long sA_b, long sB_b, long sC_b,
    float alpha, const float* __restrict__ rowbias, long sRB_b)
{
    __shared__ u16 As[128 * 32];
    __shared__ u16 Bs[128 * 32];
    const int b = blockIdx.z;
    const u16* Ab = A + (long)b * sA_b;
    const u16* Bb = B + (long)b * sB_b;
    const int i0 = blockIdx.y * 128, j0 = blockIdx.x * 128;
    const int t = threadIdx.x, wv = t >> 6, ln = t & 63;
    const int lr = ln & 15, lk = (ln >> 4) * 8;
    const int wrow = (wv >> 1) * 64, wcol = (wv & 1) * 64;

    f32x4 acc[4][4];
#pragma unroll
    for (int m = 0; m < 4; ++m)
#pragma unroll
        for (int n = 0; n < 4; ++n) acc[m][n] = (f32x4){0.f, 0.f, 0.f, 0.f};

    for (int k0 = 0; k0 < K; k0 += 32) {
        // stage A-tile [128][32] and B-tile [128][32] (8KB each) via async LDS DMA.
        // thread t stages 16B at LDS byteoff (t+256e)*16; row=byteoff/64.
#pragma unroll
        for (int e = 0; e < 2; ++e) {
            const int byteoff = (t + 256 * e) * 16;
            const int row = byteoff >> 6;
            const int cole = (byteoff & 63) >> 1;   // element offset within row
            const u16* ga = Ab + (long)(i0 + row) * K + (k0 + cole);
            const u16* gb = Bb + (long)(j0 + row) * K + (k0 + cole);
            __builtin_amdgcn_global_load_lds(
                (const __attribute__((address_space(1))) unsigned*)ga,
                (__attribute__((address_space(3))) unsigned*)&As[e * 2048 + wv * 512],
                16, 0, 0);
            __builtin_amdgcn_global_load_lds(
                (const __attribute__((address_space(1))) unsigned*)gb,
                (__attribute__((address_space(3))) unsigned*)&Bs[e * 2048 + wv * 512],
                16, 0, 0);
        }
        __syncthreads();

        bf16x8 af[4], bf[4];
#pragma unroll
        for (int m = 0; m < 4; ++m)
            af[m] = *(const bf16x8*)&As[(wrow + m * 16 + lr) * 32 + lk];
#pragma unroll
        for (int n = 0; n < 4; ++n)
            bf[n] = *(const bf16x8*)&Bs[(wcol + n * 16 + lr) * 32 + lk];
#pragma unroll
        for (int m = 0; m < 4; ++m)
#pragma unroll
            for (int n = 0; n < 4; ++n)
                acc[m][n] = __builtin_amdgcn_mfma_f32_16x16x32_bf16(
                    af[m], bf[n], acc[m][n], 0, 0, 0);
        __syncthreads();
    }

    // epilogue: C/D frag col = lane&15, row = (lane>>4)*4 + r
    const int rbase = (ln >> 4) * 4;
    if (OUT_BF16) {
        u16* C = (u16*)Cv + (long)b * sC_b;
#pragma unroll
        for (int m = 0; m < 4; ++m)
#pragma unroll
            for (int n = 0; n < 4; ++n) {
                const int col = j0 + wcol + n * 16 + lr;
                const float bias = rowbias ? rowbias[(long)b * sRB_b + col] : 0.0f;
#pragma unroll
                for (int r = 0; r < 4; ++r) {
                    const int rowi = i0 + wrow + m * 16 + rbase + r;
                    C[(long)rowi * N + col] = f2bf(acc[m][n][r] * alpha + bias);
                }
            }
    } else {
        float* C = (float*)Cv + (long)b * sC_b;
#pragma unroll
        for (int m = 0; m < 4; ++m)
#pragma unroll
            for (int n = 0; n < 4; ++n) {
                const int col = j0 + wcol + n * 16 + lr;
                const float bias = rowbias ? rowbias[(long)b * sRB_b + col] : 0.0f;
#pragma unroll
                for (int r = 0; r < 4; ++r) {
                    const int rowi = i0 + wrow + m * 16 + rbase + r;
                    C[(long)rowi * N + col] = acc[m][n][r] * alpha + bias;
                }
            }
    }
}

// ---------------- helpers -------------------------------------------------
__global__ void zero_kernel(float* __restrict__ p, int n) {
    int i = blockIdx.x * 256 + threadIdx.x;
    if (i < n) p[i] = 0.0f;
}

// s[b][d] += partial column sums of X[b][l0..l0+LC)[d]
__global__ void colsum_atomic(const float* __restrict__ X, float* __restrict__ s,
                              int L, int D, int LC) {
    int b = blockIdx.z;
    int d = blockIdx.x * 256 + threadIdx.x;
    int l0 = blockIdx.y * LC;
    const float* Xb = X + (long)b * L * D;
    float acc = 0.0f;
    for (int l = l0; l < l0 + LC; ++l) acc += Xb[(long)l * D + d];
    atomicAdd(&s[(long)b * D + d], acc);
}

// y[b][j] = alpha * sum_i x[b][i] * A(i,j), fp32 A
__global__ void matvec_kernel(const float* __restrict__ A, const float* __restrict__ x,
                              float* __restrict__ y, int NI,
                              long sA_i, long sA_j, long sA_b,
                              long sx_b, long sy_b, float alpha) {
    int b = blockIdx.y;
    int j = blockIdx.x * 256 + threadIdx.x;
    const float* Ab = A + (long)b * sA_b;
    const float* xb = x + (long)b * sx_b;
    float acc = 0.0f;
    for (int i = 0; i < NI; ++i) acc += xb[i] * Ab[(long)i * sA_i + (long)j * sA_j];
    y[(long)b * sy_b + j] = acc * alpha;
}

// y[b][j] = alpha * sum_i x[i] * A_bf16[b][j*NI + i]
__global__ void matvec_rowdot_bf16(const u16* __restrict__ A, const float* __restrict__ x,
                                   float* __restrict__ y, int NI,
                                   long sA_b, long sy_b, float alpha) {
    int b = blockIdx.y;
    int j = blockIdx.x * 256 + threadIdx.x;
    const u16* Ab = A + (long)b * sA_b + (long)j * NI;
    float acc = 0.0f;
    for (int i = 0; i < NI; ++i) acc += x[i] * bf2f(Ab[i]);
    y[(long)b * sy_b + j] = acc * alpha;
}

// E2[b][h'][h] += u[b][h]*bv[h'] + bk[h]*w[b][h'] + L*bk[h]*bv[h']  (bf16 RMW;
// skipped when the addend is exactly 0 so the zero-bias case stays exact)
__global__ void rank1_bf16(u16* __restrict__ E2, const float* __restrict__ u,
                           const float* __restrict__ bv, const float* __restrict__ bk,
                           const float* __restrict__ w, float Lf, int H) {
    int b = blockIdx.y;
    long idx = (long)blockIdx.x * 256 + threadIdx.x;
    int hp = (int)(idx / H), h = (int)(idx % H);
    float add = u[(long)b * H + h] * bv[hp] + bk[h] * w[(long)b * H + hp]
              + Lf * bk[h] * bv[hp];
    if (add != 0.0f) {
        long o = (long)b * H * H + idx;
        E2[o] = f2bf(bf2f(E2[o]) + add);
    }
}

// out[b][c][r] = bf16(in[b][r][c]); in [R,C] fp32 per batch
__global__ __launch_bounds__(256) void transpose_convert(
    const float* __restrict__ in, u16* __restrict__ outp, int R, int C) {
    __shared__ float tile[64][65];
    int b = blockIdx.z;
    int r0 = blockIdx.y * 64, c0 = blockIdx.x * 64;
    const float* ib = in + (long)b * R * C;
    u16* ob = outp + (long)b * R * C;
    int t = threadIdx.x, cc = t & 63, rr = t >> 6;
#pragma unroll
    for (int i = 0; i < 16; ++i)
        tile[rr + 4 * i][cc] = ib[(long)(r0 + rr + 4 * i) * C + c0 + cc];
    __syncthreads();
#pragma unroll
    for (int i = 0; i < 16; ++i)
        ob[(long)(c0 + rr + 4 * i) * R + r0 + cc] = f2bf(tile[cc][rr + 4 * i]);
}

// out_bf16[i] = bf16(in_f32[i]), 4 elems/thread
__global__ void convert_bf16_kernel(const float* __restrict__ in, u16* __restrict__ out,
                                    long n4) {
    long i = (long)blockIdx.x * 256 + threadIdx.x;
    if (i >= n4) return;
    float4 v = ((const float4*)in)[i];
    union { u16 h[4]; uint2 u; } r;
    r.h[0] = f2bf(v.x); r.h[1] = f2bf(v.y); r.h[2] = f2bf(v.z); r.h[3] = f2bf(v.w);
    ((uint2*)out)[i] = r.u;
}

// ---------------- launch --------------------------------------------------
extern "C" void kernel_launch(void* const* d_in, const int* in_sizes, int n_in,
                              void* d_out, int out_size, void* d_ws, size_t ws_size,
                              hipStream_t stream) {
    const float* q  = (const float*)d_in[0];
    const float* x  = (const float*)d_in[1];
    const float* Wq = (const float*)d_in[2];
    const float* bq = (const float*)d_in[3];
    const float* Wk = (const float*)d_in[4];
    const float* bk = (const float*)d_in[5];
    const float* Wv = (const float*)d_in[6];
    const float* bv = (const float*)d_in[7];
    float* out = (float*)d_out;

    const int Bn = 16, LQ = 2048, LKV = 2048, D = 512, H = 512;
    const float scale = 1.0f / sqrtf((float)H);

    char* p = (char*)d_ws;
    u16* Xt  = (u16*)p;                 // [16][512][2048] bf16, 32MB; reused as qbf
    p += (size_t)Bn * D * LKV * 2;
    u16* G   = (u16*)p; p += (size_t)Bn * D * D * 2;   // 8MB; reused as Ft
    u16* A1  = (u16*)p; p += (size_t)Bn * H * D * 2;   // 8MB
    u16* E2  = (u16*)p; p += (size_t)Bn * H * H * 2;   // 8MB
    u16* Wkb = (u16*)p; p += (size_t)H * D * 2;
    u16* Wvb = (u16*)p; p += (size_t)H * D * 2;
    u16* WqT = (u16*)p; p += (size_t)D * H * 2;        // [D][H] = Wq^T
    float* s  = (float*)p; p += (size_t)Bn * D * 4;
    float* u  = (float*)p; p += (size_t)Bn * H * 4;
    float* w  = (float*)p; p += (size_t)Bn * H * 4;
    float* f0 = (float*)p; p += (size_t)Bn * H * 4;
    u16* qbf = Xt;
    u16* Ft  = G;

    // bias plumbing (exact; zero-bias case contributes exactly 0)
    zero_kernel<<<dim3((Bn * D + 255) / 256), dim3(256), 0, stream>>>(s, Bn * D);
    colsum_atomic<<<dim3(D / 256, 8, Bn), dim3(256), 0, stream>>>(x, s, LKV, D, LKV / 8);
    matvec_kernel<<<dim3(H / 256, Bn), dim3(256), 0, stream>>>(
        Wk, s, u, D, 1L, (long)D, 0L, (long)D, (long)H, 1.0f);
    matvec_kernel<<<dim3(H / 256, Bn), dim3(256), 0, stream>>>(
        Wv, s, w, D, 1L, (long)D, 0L, (long)D, (long)H, 1.0f);

    // bf16 conversions
    transpose_convert<<<dim3(D / 64, LKV / 64, Bn), dim3(256), 0, stream>>>(x, Xt, LKV, D);
    transpose_convert<<<dim3(D / 64, H / 64, 1), dim3(256), 0, stream>>>(Wq, WqT, H, D);
    convert_bf16_kernel<<<dim3((H * D / 4 + 255) / 256), dim3(256), 0, stream>>>(
        Wk, Wkb, (long)H * D / 4);
    convert_bf16_kernel<<<dim3((H * D / 4 + 255) / 256), dim3(256), 0, stream>>>(
        Wv, Wvb, (long)H * D / 4);

    // G = Xt Xt^T  (M=N=512, K=2048)
    gemm_bt<true><<<dim3(D / 128, D / 128, Bn), dim3(256), 0, stream>>>(
        Xt, Xt, G, D, D, LKV,
        (long)D * LKV, (long)D * LKV, (long)D * D, 1.0f, nullptr, 0L);

    // q -> bf16 into Xt slot (Xt dead after G)
    convert_bf16_kernel<<<dim3((int)(((long)Bn * LQ * D / 4 + 255) / 256)), dim3(256), 0, stream>>>(
        q, qbf, (long)Bn * LQ * D / 4);

    // A1 = Wk G  (G symmetric so B-op = G works)
    gemm_bt<true><<<dim3(D / 128, H / 128, Bn), dim3(256), 0, stream>>>(
        Wkb, G, A1, H, D, D,
        0L, (long)D * D, (long)H * D, 1.0f, nullptr, 0L);

    // E2 = Wv A1^T  (= E^T)
    gemm_bt<true><<<dim3(H / 128, H / 128, Bn), dim3(256), 0, stream>>>(
        Wvb, A1, E2, H, H, D,
        0L, (long)H * D, (long)H * H, 1.0f, nullptr, 0L);

    // rank-1 bias fixups on E2 (exact no-op when biases are zero)
    rank1_bf16<<<dim3(H * H / 256, Bn), dim3(256), 0, stream>>>(E2, u, bv, bk, w,
                                                                (float)LKV, H);
    // f0 = scale * bq^T E   (f0[h'] = scale * sum_h bq[h] E2[h'][h])
    matvec_rowdot_bf16<<<dim3(H / 256, Bn), dim3(256), 0, stream>>>(
        E2, bq, f0, H, (long)H * H, (long)H, scale);

    // Ft = scale * E2 Wq  (Ft[h'][d]; B-op = Wq^T stored [D][H])
    gemm_bt<true><<<dim3(D / 128, H / 128, Bn), dim3(256), 0, stream>>>(
        E2, WqT, Ft, H, D, H,
        (long)H * H, 0L, (long)H * D, scale, nullptr, 0L);

    // ctx = q F + 1 f0^T  (M=2048, N=512, K=512; B-op = Ft)
    gemm_bt<false><<<dim3(H / 128, LQ / 128, Bn), dim3(256), 0, stream>>>(
        qbf, Ft, out, LQ, H, D,
        (long)LQ * D, (long)H * D, (long)LQ * H, 1.0f, f0, (long)H);
}

// Round 3
// 327.342 us; speedup vs baseline: 5.7650x; 1.3846x over previous
//
#include <hip/hip_runtime.h>
#include <math.h>

// B=16, LQ=LKV=2048, D=H=512, fp32 in/out. No softmax -> reassociate:
//   G_b = X_b^T X_b                     [512,512] (K=2048, exactly symmetric)
//   P   = scale * Wq^T Wk               [512,512] (batch-independent)
//   T2_b= Wv G_b                        [512,512]
//   Ft_b= T2_b P^T  (= F^T, F = scale Wq^T Wk G Wv^T)
//   ctx = q F + 1 f0^T                  (rowbias f0 from bias chain; 0 here)
// All GEMMs: C[M,N] = alpha*A[M,K]*B[N,K]^T, bf16 K-contiguous operands,
// m97-structure MFMA (128x128 tile, 4 waves, global_load_lds w=16).

typedef unsigned short u16;
typedef __attribute__((ext_vector_type(8))) short bf16x8;
typedef __attribute__((ext_vector_type(4))) float f32x4;

__device__ __forceinline__ u16 f2bf(float f) {
    union { float f; unsigned u; } a; a.f = f;
    unsigned r = a.u + 0x7FFFu + ((a.u >> 16) & 1u);
    return (u16)(r >> 16);
}
__device__ __forceinline__ float bf2f(u16 h) {
    union { unsigned u; float f; } a; a.u = ((unsigned)h) << 16;
    return a.f;
}

// ---------------- MFMA GEMM: C[M,N] = alpha * A[M,K] B[N,K]^T (+rowbias[j]) ---
template<bool OUT_BF16>
__global__ __launch_bounds__(256) void gemm_bt(
    const u16* __restrict__ A, const u16* __restrict__ B, void* __restrict__ Cv,
    int M, int N, int K,
    long sA_b, long sB_b, long sC_b,
    float alpha, const float* __restrict__ rowbias, long sRB_b)
{
    __shared__ u16 As[128 * 32];
    __shared__ u16 Bs[128 * 32];
    const int b = blockIdx.z;
    const u16* Ab = A + (long)b * sA_b;
    const u16* Bb = B + (long)b * sB_b;
    const int i0 = blockIdx.y * 128, j0 = blockIdx.x * 128;
    const int t = threadIdx.x, wv = t >> 6, ln = t & 63;
    const int lr = ln & 15, lk = (ln >> 4) * 8;
    const int wrow = (wv >> 1) * 64, wcol = (wv & 1) * 64;

    f32x4 acc[4][4];
#pragma unroll
    for (int m = 0; m < 4; ++m)
#pragma unroll
        for (int n = 0; n < 4; ++n) acc[m][n] = (f32x4){0.f, 0.f, 0.f, 0.f};

    for (int k0 = 0; k0 < K; k0 += 32) {
#pragma unroll
        for (int e = 0; e < 2; ++e) {
            const int byteoff = (t + 256 * e) * 16;
            const int row = byteoff >> 6;
            const int cole = (byteoff & 63) >> 1;
            const u16* ga = Ab + (long)(i0 + row) * K + (k0 + cole);
            const u16* gb = Bb + (long)(j0 + row) * K + (k0 + cole);
            __builtin_amdgcn_global_load_lds(
                (const __attribute__((address_space(1))) unsigned*)ga,
                (__attribute__((address_space(3))) unsigned*)&As[e * 2048 + wv * 512],
                16, 0, 0);
            __builtin_amdgcn_global_load_lds(
                (const __attribute__((address_space(1))) unsigned*)gb,
                (__attribute__((address_space(3))) unsigned*)&Bs[e * 2048 + wv * 512],
                16, 0, 0);
        }
        __syncthreads();

        bf16x8 af[4], bf[4];
#pragma unroll
        for (int m = 0; m < 4; ++m)
            af[m] = *(const bf16x8*)&As[(wrow + m * 16 + lr) * 32 + lk];
#pragma unroll
        for (int n = 0; n < 4; ++n)
            bf[n] = *(const bf16x8*)&Bs[(wcol + n * 16 + lr) * 32 + lk];
#pragma unroll
        for (int m = 0; m < 4; ++m)
#pragma unroll
            for (int n = 0; n < 4; ++n)
                acc[m][n] = __builtin_amdgcn_mfma_f32_16x16x32_bf16(
                    af[m], bf[n], acc[m][n], 0, 0, 0);
        __syncthreads();
    }

    const int rbase = (ln >> 4) * 4;
    if (OUT_BF16) {
        u16* C = (u16*)Cv + (long)b * sC_b;
#pragma unroll
        for (int m = 0; m < 4; ++m)
#pragma unroll
            for (int n = 0; n < 4; ++n) {
                const int col = j0 + wcol + n * 16 + lr;
#pragma unroll
                for (int r = 0; r < 4; ++r) {
                    const int rowi = i0 + wrow + m * 16 + rbase + r;
                    C[(long)rowi * N + col] = f2bf(acc[m][n][r] * alpha);
                }
            }
    } else {
        float* C = (float*)Cv + (long)b * sC_b;
#pragma unroll
        for (int m = 0; m < 4; ++m)
#pragma unroll
            for (int n = 0; n < 4; ++n) {
                const int col = j0 + wcol + n * 16 + lr;
                const float bias = rowbias ? rowbias[(long)b * sRB_b + col] : 0.0f;
#pragma unroll
                for (int r = 0; r < 4; ++r) {
                    const int rowi = i0 + wrow + m * 16 + rbase + r;
                    C[(long)rowi * N + col] = acc[m][n][r] * alpha + bias;
                }
            }
    }
}

// ---------------- x: transpose+convert+fused column partial sums ------------
// X [b][2048][512] f32 -> Xt [b][512][2048] bf16 ; partials[b][32][512]
__global__ __launch_bounds__(256) void transpose_x_colsum(
    const float* __restrict__ in, u16* __restrict__ outp, float* __restrict__ partials)
{
    __shared__ float tile[64][65];
    __shared__ float cp[4][64];
    const int R = 2048, C = 512;
    int b = blockIdx.z;
    int r0 = blockIdx.y * 64, c0 = blockIdx.x * 64;
    const float* ib = in + (long)b * R * C;
    u16* ob = outp + (long)b * R * C;
    int t = threadIdx.x, cc = t & 63, rr = t >> 6;
    float acc = 0.f;
#pragma unroll
    for (int i = 0; i < 16; ++i) {
        float v = ib[(long)(r0 + rr + 4 * i) * C + c0 + cc];
        tile[rr + 4 * i][cc] = v;
        acc += v;
    }
    cp[rr][cc] = acc;
    __syncthreads();
#pragma unroll
    for (int i = 0; i < 16; ++i)
        ob[(long)(c0 + rr + 4 * i) * R + r0 + cc] = f2bf(tile[cc][rr + 4 * i]);
    if (rr == 0)
        partials[((long)b * 32 + blockIdx.y) * 512 + c0 + cc] =
            cp[0][cc] + cp[1][cc] + cp[2][cc] + cp[3][cc];
}

// ---------------- weights: WqT, WkT (transpose), Wvb (straight) -------------
__global__ __launch_bounds__(256) void weights_prep(
    const float* __restrict__ Wq, const float* __restrict__ Wk, const float* __restrict__ Wv,
    u16* __restrict__ WqT, u16* __restrict__ WkT, u16* __restrict__ Wvb)
{
    __shared__ float tile[64][65];
    const int N = 512;
    int z = blockIdx.z;
    int r0 = blockIdx.y * 64, c0 = blockIdx.x * 64;
    const float* ib = z == 0 ? Wq : (z == 1 ? Wk : Wv);
    u16* ob = z == 0 ? WqT : (z == 1 ? WkT : Wvb);
    int t = threadIdx.x, cc = t & 63, rr = t >> 6;
    if (z == 2) {
#pragma unroll
        for (int i = 0; i < 16; ++i) {
            long o = (long)(r0 + rr + 4 * i) * N + c0 + cc;
            ob[o] = f2bf(ib[o]);
        }
        return;
    }
#pragma unroll
    for (int i = 0; i < 16; ++i)
        tile[rr + 4 * i][cc] = ib[(long)(r0 + rr + 4 * i) * N + c0 + cc];
    __syncthreads();
#pragma unroll
    for (int i = 0; i < 16; ++i)
        ob[(long)(c0 + rr + 4 * i) * N + r0 + cc] = f2bf(tile[cc][rr + 4 * i]);
}

__global__ void convert_bf16_kernel(const float* __restrict__ in, u16* __restrict__ out,
                                    long n4) {
    long i = (long)blockIdx.x * 256 + threadIdx.x;
    if (i >= n4) return;
    float4 v = ((const float4*)in)[i];
    union { u16 h[4]; uint2 u; } r;
    r.h[0] = f2bf(v.x); r.h[1] = f2bf(v.y); r.h[2] = f2bf(v.z); r.h[3] = f2bf(v.w);
    ((uint2*)out)[i] = r.u;
}

// ---------------- bias plumbing (exact; all-zero for this problem's inputs) -
// grid (2,16), 512 thr. x=0: u_b = Wk s_b (+b0: a=Wk^T bq, vqk=Wq^T bk); x=1: w_b = Wv s_b
__global__ __launch_bounds__(512) void bias_pre(
    const float* __restrict__ partials, const float* __restrict__ Wk,
    const float* __restrict__ Wv, const float* __restrict__ Wq,
    const float* __restrict__ bq, const float* __restrict__ bk,
    float* __restrict__ u, float* __restrict__ w,
    float* __restrict__ a, float* __restrict__ vqk)
{
    __shared__ float s_sh[512];
    int b = blockIdx.y, t = threadIdx.x;
    float acc = 0.f;
    for (int j = 0; j < 32; ++j) acc += partials[((long)b * 32 + j) * 512 + t];
    s_sh[t] = acc;
    __syncthreads();
    const float* W = blockIdx.x == 0 ? Wk : Wv;
    float* outv = blockIdx.x == 0 ? u : w;
    int wv = t >> 6, ln = t & 63;
    for (int hh = 0; hh < 64; ++hh) {
        int h = wv * 64 + hh;
        float p = 0.f;
#pragma unroll
        for (int c = 0; c < 8; ++c) p += W[(long)h * 512 + ln + 64 * c] * s_sh[ln + 64 * c];
#pragma unroll
        for (int m = 1; m < 64; m <<= 1) p += __shfl_xor(p, m, 64);
        if (ln == 0) outv[(long)b * 512 + h] = p;
    }
    if (blockIdx.x == 0 && b == 0) {
        float pa = 0.f, pv = 0.f;
        for (int h = 0; h < 512; ++h) {
            pa += bq[h] * Wk[(long)h * 512 + t];
            pv += Wq[(long)h * 512 + t] * bk[h];
        }
        a[t] = pa; vqk[t] = pv;
    }
}

// grid 16: bvec_b = G_b a (G symmetric -> coalesced column reads)
__global__ __launch_bounds__(512) void bias_mid(
    const u16* __restrict__ G, const float* __restrict__ a, float* __restrict__ bvec)
{
    __shared__ float a_sh[512];
    int b = blockIdx.x, t = threadIdx.x;
    a_sh[t] = a[t];
    __syncthreads();
    const u16* Gb = G + (long)b * 512 * 512;
    float acc = 0.f;
    for (int j = 0; j < 512; ++j) acc += a_sh[j] * bf2f(Gb[(long)j * 512 + t]);
    bvec[(long)b * 512 + t] = acc;
}

// grid 16: vqu_b = Wq^T u_b ; c = Wv bvec_b ; f0 = scale*(c + d1 bv + d2 w + L d2 bv)
__global__ __launch_bounds__(512) void bias_post(
    const float* __restrict__ Wq, const float* __restrict__ Wv,
    const float* __restrict__ u, const float* __restrict__ w,
    const float* __restrict__ bvec,
    const float* __restrict__ bq, const float* __restrict__ bk, const float* __restrict__ bv,
    float* __restrict__ vqu, float* __restrict__ f0, float scale, float Lf)
{
    __shared__ float u_sh[512], b_sh[512];
    int b = blockIdx.x, t = threadIdx.x;
    u_sh[t] = u[(long)b * 512 + t];
    b_sh[t] = bvec[(long)b * 512 + t];
    __syncthreads();
    float pv = 0.f;
    for (int h = 0; h < 512; ++h) pv += Wq[(long)h * 512 + t] * u_sh[h];
    vqu[(long)b * 512 + t] = pv;
    float d1 = 0.f, d2 = 0.f;
    for (int h = 0; h < 512; ++h) { d1 += bq[h] * u_sh[h]; d2 += bq[h] * bk[h]; }
    int wv = t >> 6, ln = t & 63;
    for (int hh = 0; hh < 64; ++hh) {
        int hp = wv * 64 + hh;
        float p = 0.f;
#pragma unroll
        for (int c = 0; c < 8; ++c) p += Wv[(long)hp * 512 + ln + 64 * c] * b_sh[ln + 64 * c];
#pragma unroll
        for (int m = 1; m < 64; m <<= 1) p += __shfl_xor(p, m, 64);
        if (ln == 0)
            f0[(long)b * 512 + hp] =
                scale * (p + d1 * bv[hp] + d2 * w[(long)b * 512 + hp] + Lf * d2 * bv[hp]);
    }
}

// grid (1024,16): Ft[b][hp][d] += scale*(bv[hp]vqu[b][d] + w[b][hp]vqk[d] + L bv[hp]vqk[d])
__global__ void rank1F(u16* __restrict__ Ft, const float* __restrict__ bv,
                       const float* __restrict__ vqu, const float* __restrict__ w,
                       const float* __restrict__ vqk, float scale, float Lf)
{
    int b = blockIdx.y;
    long idx = (long)blockIdx.x * 256 + threadIdx.x;
    int hp = (int)(idx >> 9), d = (int)(idx & 511);
    float add = scale * (bv[hp] * vqu[(long)b * 512 + d] + w[(long)b * 512 + hp] * vqk[d]
                         + Lf * bv[hp] * vqk[d]);
    if (add != 0.f) {
        long o = (long)b * 512 * 512 + idx;
        Ft[o] = f2bf(bf2f(Ft[o]) + add);
    }
}

// ---------------- launch --------------------------------------------------
extern "C" void kernel_launch(void* const* d_in, const int* in_sizes, int n_in,
                              void* d_out, int out_size, void* d_ws, size_t ws_size,
                              hipStream_t stream) {
    const float* q  = (const float*)d_in[0];
    const float* x  = (const float*)d_in[1];
    const float* Wq = (const float*)d_in[2];
    const float* bq = (const float*)d_in[3];
    const float* Wk = (const float*)d_in[4];
    const float* bk = (const float*)d_in[5];
    const float* Wv = (const float*)d_in[6];
    const float* bv = (const float*)d_in[7];
    float* out = (float*)d_out;

    const int Bn = 16, LQ = 2048, LKV = 2048, D = 512, H = 512;
    const float scale = 1.0f / sqrtf((float)H);

    char* p = (char*)d_ws;
    u16* Xt   = (u16*)p; p += (size_t)Bn * D * LKV * 2;   // 32MB; reused as qbf
    u16* G    = (u16*)p; p += (size_t)Bn * D * D * 2;     // 8MB; reused as Ft
    u16* T2   = (u16*)p; p += (size_t)Bn * H * D * 2;     // 8MB
    u16* P    = (u16*)p; p += (size_t)D * H * 2;
    u16* WqT  = (u16*)p; p += (size_t)D * H * 2;
    u16* WkT  = (u16*)p; p += (size_t)D * H * 2;
    u16* Wvb  = (u16*)p; p += (size_t)H * D * 2;
    float* partials = (float*)p; p += (size_t)Bn * 32 * D * 4;  // 1MB
    float* u    = (float*)p; p += (size_t)Bn * H * 4;
    float* w    = (float*)p; p += (size_t)Bn * H * 4;
    float* bvec = (float*)p; p += (size_t)Bn * D * 4;
    float* vqu  = (float*)p; p += (size_t)Bn * D * 4;
    float* f0   = (float*)p; p += (size_t)Bn * H * 4;
    float* a    = (float*)p; p += (size_t)D * 4;
    float* vqk  = (float*)p; p += (size_t)D * 4;
    u16* qbf = Xt;
    u16* Ft  = G;

    // 1) X -> Xt (bf16, transposed) + column-sum partials
    transpose_x_colsum<<<dim3(D / 64, LKV / 64, Bn), dim3(256), 0, stream>>>(
        x, Xt, partials);

    // 2) weights -> WqT, WkT, Wvb
    weights_prep<<<dim3(8, 8, 3), dim3(256), 0, stream>>>(Wq, Wk, Wv, WqT, WkT, Wvb);

    // 3) P = scale * Wq^T Wk
    gemm_bt<true><<<dim3(4, 4, 1), dim3(256), 0, stream>>>(
        WqT, WkT, P, D, H, H, 0L, 0L, 0L, scale, nullptr, 0L);

    // 4) bias vectors stage 1
    bias_pre<<<dim3(2, Bn), dim3(512), 0, stream>>>(partials, Wk, Wv, Wq, bq, bk,
                                                    u, w, a, vqk);

    // 5) G = Xt Xt^T  (K=2048)
    gemm_bt<true><<<dim3(4, 4, Bn), dim3(256), 0, stream>>>(
        Xt, Xt, G, D, D, LKV,
        (long)D * LKV, (long)D * LKV, (long)D * D, 1.0f, nullptr, 0L);

    // 6) q -> bf16 (Xt slot dead after G)
    convert_bf16_kernel<<<dim3((int)(((long)Bn * LQ * D / 4 + 255) / 256)), dim3(256),
                          0, stream>>>(q, qbf, (long)Bn * LQ * D / 4);

    // 7) bvec = G a
    bias_mid<<<dim3(Bn), dim3(512), 0, stream>>>(G, a, bvec);

    // 8) T2 = Wv G
    gemm_bt<true><<<dim3(4, 4, Bn), dim3(256), 0, stream>>>(
        Wvb, G, T2, H, D, D,
        0L, (long)D * D, (long)H * D, 1.0f, nullptr, 0L);

    // 9) bias vectors stage 2
    bias_post<<<dim3(Bn), dim3(512), 0, stream>>>(Wq, Wv, u, w, bvec, bq, bk, bv,
                                                  vqu, f0, scale, (float)LKV);

    // 10) Ft = T2 P^T  (overwrites G slot; G last read in step 8)
    gemm_bt<true><<<dim3(4, 4, Bn), dim3(256), 0, stream>>>(
        T2, P, Ft, H, D, H,
        (long)H * D, 0L, (long)H * D, 1.0f, nullptr, 0L);

    // 11) rank-1 bias fixup on Ft (exact no-op for zero biases)
    rank1F<<<dim3(1024, Bn), dim3(256), 0, stream>>>(Ft, bv, vqu, w, vqk,
                                                     scale, (float)LKV);

    // 12) ctx = q F + 1 f0^T
    gemm_bt<false><<<dim3(4, 16, Bn), dim3(256), 0, stream>>>(
        qbf, Ft, out, LQ, H, D,
        (long)LQ * D, (long)H * D, (long)LQ * H, 1.0f, f0, (long)H);
}

// Round 4
// 187.037 us; speedup vs baseline: 10.0895x; 1.7501x over previous
//
#include <hip/hip_runtime.h>
#include <math.h>

// B=16, LQ=LKV=2048, D=H=512, fp32 in/out. No softmax -> reassociate:
//   G_b = X_b^T X_b                     [512,512] (K=2048, exactly symmetric)
//   P   = scale * Wq^T Wk               [512,512] (batch-independent)
//   T2_b= Wv G_b                        [512,512]
//   Ft_b= T2_b P^T  (= F^T, F = scale Wq^T Wk G Wv^T)
//   ctx = q F + 1 f0^T
// Bias corrections are exact but guarded by a device-side flag: when
// bq=bk=bv=0 (this problem's inputs) the bias kernels early-exit.
// All GEMMs: C[M,N] = alpha*A[M,K]*B[N,K]^T, bf16 K-contiguous operands,
// m97-structure MFMA (128x128 tile, 4 waves, global_load_lds w=16).

typedef unsigned short u16;
typedef __attribute__((ext_vector_type(8))) short bf16x8;
typedef __attribute__((ext_vector_type(4))) float f32x4;

__device__ __forceinline__ u16 f2bf(float f) {
    union { float f; unsigned u; } a; a.f = f;
    unsigned r = a.u + 0x7FFFu + ((a.u >> 16) & 1u);
    return (u16)(r >> 16);
}
__device__ __forceinline__ float bf2f(u16 h) {
    union { unsigned u; float f; } a; a.u = ((unsigned)h) << 16;
    return a.f;
}

// ---------------- MFMA GEMM: C[M,N] = alpha * A[M,K] B[N,K]^T (+rowbias[j]) ---
template<bool OUT_BF16>
__global__ __launch_bounds__(256) void gemm_bt(
    const u16* __restrict__ A, const u16* __restrict__ B, void* __restrict__ Cv,
    int M, int N, int K,
    long sA_b, long sB_b, long sC_b,
    float alpha, const float* __restrict__ rowbias, long sRB_b)
{
    __shared__ u16 As[128 * 32];
    __shared__ u16 Bs[128 * 32];
    const int b = blockIdx.z;
    const u16* Ab = A + (long)b * sA_b;
    const u16* Bb = B + (long)b * sB_b;
    const int i0 = blockIdx.y * 128, j0 = blockIdx.x * 128;
    const int t = threadIdx.x, wv = t >> 6, ln = t & 63;
    const int lr = ln & 15, lk = (ln >> 4) * 8;
    const int wrow = (wv >> 1) * 64, wcol = (wv & 1) * 64;

    f32x4 acc[4][4];
#pragma unroll
    for (int m = 0; m < 4; ++m)
#pragma unroll
        for (int n = 0; n < 4; ++n) acc[m][n] = (f32x4){0.f, 0.f, 0.f, 0.f};

    for (int k0 = 0; k0 < K; k0 += 32) {
#pragma unroll
        for (int e = 0; e < 2; ++e) {
            const int byteoff = (t + 256 * e) * 16;
            const int row = byteoff >> 6;
            const int cole = (byteoff & 63) >> 1;
            const u16* ga = Ab + (long)(i0 + row) * K + (k0 + cole);
            const u16* gb = Bb + (long)(j0 + row) * K + (k0 + cole);
            __builtin_amdgcn_global_load_lds(
                (const __attribute__((address_space(1))) unsigned*)ga,
                (__attribute__((address_space(3))) unsigned*)&As[e * 2048 + wv * 512],
                16, 0, 0);
            __builtin_amdgcn_global_load_lds(
                (const __attribute__((address_space(1))) unsigned*)gb,
                (__attribute__((address_space(3))) unsigned*)&Bs[e * 2048 + wv * 512],
                16, 0, 0);
        }
        __syncthreads();

        bf16x8 af[4], bf[4];
#pragma unroll
        for (int m = 0; m < 4; ++m)
            af[m] = *(const bf16x8*)&As[(wrow + m * 16 + lr) * 32 + lk];
#pragma unroll
        for (int n = 0; n < 4; ++n)
            bf[n] = *(const bf16x8*)&Bs[(wcol + n * 16 + lr) * 32 + lk];
#pragma unroll
        for (int m = 0; m < 4; ++m)
#pragma unroll
            for (int n = 0; n < 4; ++n)
                acc[m][n] = __builtin_amdgcn_mfma_f32_16x16x32_bf16(
                    af[m], bf[n], acc[m][n], 0, 0, 0);
        __syncthreads();
    }

    const int rbase = (ln >> 4) * 4;
    if (OUT_BF16) {
        u16* C = (u16*)Cv + (long)b * sC_b;
#pragma unroll
        for (int m = 0; m < 4; ++m)
#pragma unroll
            for (int n = 0; n < 4; ++n) {
                const int col = j0 + wcol + n * 16 + lr;
#pragma unroll
                for (int r = 0; r < 4; ++r) {
                    const int rowi = i0 + wrow + m * 16 + rbase + r;
                    C[(long)rowi * N + col] = f2bf(acc[m][n][r] * alpha);
                }
            }
    } else {
        float* C = (float*)Cv + (long)b * sC_b;
#pragma unroll
        for (int m = 0; m < 4; ++m)
#pragma unroll
            for (int n = 0; n < 4; ++n) {
                const int col = j0 + wcol + n * 16 + lr;
                const float bias = rowbias ? rowbias[(long)b * sRB_b + col] : 0.0f;
#pragma unroll
                for (int r = 0; r < 4; ++r) {
                    const int rowi = i0 + wrow + m * 16 + rbase + r;
                    C[(long)rowi * N + col] = acc[m][n][r] * alpha + bias;
                }
            }
    }
}

// ---------------- x: transpose+convert+fused column partial sums ------------
__global__ __launch_bounds__(256) void transpose_x_colsum(
    const float* __restrict__ in, u16* __restrict__ outp, float* __restrict__ partials)
{
    __shared__ float tile[64][65];
    __shared__ float cp[4][64];
    const int R = 2048, C = 512;
    int b = blockIdx.z;
    int r0 = blockIdx.y * 64, c0 = blockIdx.x * 64;
    const float* ib = in + (long)b * R * C;
    u16* ob = outp + (long)b * R * C;
    int t = threadIdx.x, cc = t & 63, rr = t >> 6;
    float acc = 0.f;
#pragma unroll
    for (int i = 0; i < 16; ++i) {
        float v = ib[(long)(r0 + rr + 4 * i) * C + c0 + cc];
        tile[rr + 4 * i][cc] = v;
        acc += v;
    }
    cp[rr][cc] = acc;
    __syncthreads();
#pragma unroll
    for (int i = 0; i < 16; ++i)
        ob[(long)(c0 + rr + 4 * i) * R + r0 + cc] = f2bf(tile[cc][rr + 4 * i]);
    if (rr == 0)
        partials[((long)b * 32 + blockIdx.y) * 512 + c0 + cc] =
            cp[0][cc] + cp[1][cc] + cp[2][cc] + cp[3][cc];
}

// ---------------- weights: WqT, WkT (transpose), Wvb (straight) -------------
__global__ __launch_bounds__(256) void weights_prep(
    const float* __restrict__ Wq, const float* __restrict__ Wk, const float* __restrict__ Wv,
    u16* __restrict__ WqT, u16* __restrict__ WkT, u16* __restrict__ Wvb)
{
    __shared__ float tile[64][65];
    const int N = 512;
    int z = blockIdx.z;
    int r0 = blockIdx.y * 64, c0 = blockIdx.x * 64;
    const float* ib = z == 0 ? Wq : (z == 1 ? Wk : Wv);
    u16* ob = z == 0 ? WqT : (z == 1 ? WkT : Wvb);
    int t = threadIdx.x, cc = t & 63, rr = t >> 6;
    if (z == 2) {
#pragma unroll
        for (int i = 0; i < 16; ++i) {
            long o = (long)(r0 + rr + 4 * i) * N + c0 + cc;
            ob[o] = f2bf(ib[o]);
        }
        return;
    }
#pragma unroll
    for (int i = 0; i < 16; ++i)
        tile[rr + 4 * i][cc] = ib[(long)(r0 + rr + 4 * i) * N + c0 + cc];
    __syncthreads();
#pragma unroll
    for (int i = 0; i < 16; ++i)
        ob[(long)(c0 + rr + 4 * i) * N + r0 + cc] = f2bf(tile[cc][rr + 4 * i]);
}

__global__ void convert_bf16_kernel(const float* __restrict__ in, u16* __restrict__ out,
                                    long n4) {
    long i = (long)blockIdx.x * 256 + threadIdx.x;
    if (i >= n4) return;
    float4 v = ((const float4*)in)[i];
    union { u16 h[4]; uint2 u; } r;
    r.h[0] = f2bf(v.x); r.h[1] = f2bf(v.y); r.h[2] = f2bf(v.z); r.h[3] = f2bf(v.w);
    ((uint2*)out)[i] = r.u;
}

// ---------------- bias flag + f0 zero (1 block, 512 thr) --------------------
// flag[0] = max |bq|,|bk|,|bv|  (0 => all bias kernels early-exit); f0 = 0.
__global__ __launch_bounds__(512) void bias_flag_f0(
    const float* __restrict__ bq, const float* __restrict__ bk,
    const float* __restrict__ bv, float* __restrict__ flag, float* __restrict__ f0)
{
    __shared__ float red[8];
    int t = threadIdx.x;
    float m = fabsf(bq[t]);
    m = fmaxf(m, fabsf(bk[t]));
    m = fmaxf(m, fabsf(bv[t]));
#pragma unroll
    for (int s = 1; s < 64; s <<= 1) m = fmaxf(m, __shfl_xor(m, s, 64));
    if ((t & 63) == 0) red[t >> 6] = m;
    __syncthreads();
    if (t == 0) {
        float mm = red[0];
#pragma unroll
        for (int i = 1; i < 8; ++i) mm = fmaxf(mm, red[i]);
        flag[0] = mm;
    }
#pragma unroll
    for (int i = 0; i < 16; ++i) f0[t + 512 * i] = 0.0f;
}

// ---------------- bias plumbing (exact; early-exit when flag==0) ------------
__global__ __launch_bounds__(512) void bias_pre(
    const float* __restrict__ flag,
    const float* __restrict__ partials, const float* __restrict__ Wk,
    const float* __restrict__ Wv, const float* __restrict__ Wq,
    const float* __restrict__ bq, const float* __restrict__ bk,
    float* __restrict__ u, float* __restrict__ w,
    float* __restrict__ a, float* __restrict__ vqk)
{
    if (flag[0] == 0.0f) return;
    __shared__ float s_sh[512];
    int b = blockIdx.y, t = threadIdx.x;
    float acc = 0.f;
    for (int j = 0; j < 32; ++j) acc += partials[((long)b * 32 + j) * 512 + t];
    s_sh[t] = acc;
    __syncthreads();
    const float* W = blockIdx.x == 0 ? Wk : Wv;
    float* outv = blockIdx.x == 0 ? u : w;
    int wv = t >> 6, ln = t & 63;
    for (int hh = 0; hh < 64; ++hh) {
        int h = wv * 64 + hh;
        float p = 0.f;
#pragma unroll
        for (int c = 0; c < 8; ++c) p += W[(long)h * 512 + ln + 64 * c] * s_sh[ln + 64 * c];
#pragma unroll
        for (int m = 1; m < 64; m <<= 1) p += __shfl_xor(p, m, 64);
        if (ln == 0) outv[(long)b * 512 + h] = p;
    }
    if (blockIdx.x == 0 && b == 0) {
        float pa = 0.f, pv = 0.f;
        for (int h = 0; h < 512; ++h) {
            pa += bq[h] * Wk[(long)h * 512 + t];
            pv += Wq[(long)h * 512 + t] * bk[h];
        }
        a[t] = pa; vqk[t] = pv;
    }
}

__global__ __launch_bounds__(512) void bias_mid(
    const float* __restrict__ flag,
    const u16* __restrict__ G, const float* __restrict__ a, float* __restrict__ bvec)
{
    if (flag[0] == 0.0f) return;
    __shared__ float a_sh[512];
    int b = blockIdx.x, t = threadIdx.x;
    a_sh[t] = a[t];
    __syncthreads();
    const u16* Gb = G + (long)b * 512 * 512;
    float acc = 0.f;
    for (int j = 0; j < 512; ++j) acc += a_sh[j] * bf2f(Gb[(long)j * 512 + t]);
    bvec[(long)b * 512 + t] = acc;
}

__global__ __launch_bounds__(512) void bias_post(
    const float* __restrict__ flag,
    const float* __restrict__ Wq, const float* __restrict__ Wv,
    const float* __restrict__ u, const float* __restrict__ w,
    const float* __restrict__ bvec,
    const float* __restrict__ bq, const float* __restrict__ bk, const float* __restrict__ bv,
    float* __restrict__ vqu, float* __restrict__ f0, float scale, float Lf)
{
    if (flag[0] == 0.0f) return;
    __shared__ float u_sh[512], b_sh[512];
    int b = blockIdx.x, t = threadIdx.x;
    u_sh[t] = u[(long)b * 512 + t];
    b_sh[t] = bvec[(long)b * 512 + t];
    __syncthreads();
    float pv = 0.f;
    for (int h = 0; h < 512; ++h) pv += Wq[(long)h * 512 + t] * u_sh[h];
    vqu[(long)b * 512 + t] = pv;
    float d1 = 0.f, d2 = 0.f;
    for (int h = 0; h < 512; ++h) { d1 += bq[h] * u_sh[h]; d2 += bq[h] * bk[h]; }
    int wv = t >> 6, ln = t & 63;
    for (int hh = 0; hh < 64; ++hh) {
        int hp = wv * 64 + hh;
        float p = 0.f;
#pragma unroll
        for (int c = 0; c < 8; ++c) p += Wv[(long)hp * 512 + ln + 64 * c] * b_sh[ln + 64 * c];
#pragma unroll
        for (int m = 1; m < 64; m <<= 1) p += __shfl_xor(p, m, 64);
        if (ln == 0)
            f0[(long)b * 512 + hp] =
                scale * (p + d1 * bv[hp] + d2 * w[(long)b * 512 + hp] + Lf * d2 * bv[hp]);
    }
}

__global__ void rank1F(const float* __restrict__ flag,
                       u16* __restrict__ Ft, const float* __restrict__ bv,
                       const float* __restrict__ vqu, const float* __restrict__ w,
                       const float* __restrict__ vqk, float scale, float Lf)
{
    if (flag[0] == 0.0f) return;
    int b = blockIdx.y;
    long idx = (long)blockIdx.x * 256 + threadIdx.x;
    int hp = (int)(idx >> 9), d = (int)(idx & 511);
    float add = scale * (bv[hp] * vqu[(long)b * 512 + d] + w[(long)b * 512 + hp] * vqk[d]
                         + Lf * bv[hp] * vqk[d]);
    if (add != 0.f) {
        long o = (long)b * 512 * 512 + idx;
        Ft[o] = f2bf(bf2f(Ft[o]) + add);
    }
}

// ---------------- launch --------------------------------------------------
extern "C" void kernel_launch(void* const* d_in, const int* in_sizes, int n_in,
                              void* d_out, int out_size, void* d_ws, size_t ws_size,
                              hipStream_t stream) {
    const float* q  = (const float*)d_in[0];
    const float* x  = (const float*)d_in[1];
    const float* Wq = (const float*)d_in[2];
    const float* bq = (const float*)d_in[3];
    const float* Wk = (const float*)d_in[4];
    const float* bk = (const float*)d_in[5];
    const float* Wv = (const float*)d_in[6];
    const float* bv = (const float*)d_in[7];
    float* out = (float*)d_out;

    const int Bn = 16, LQ = 2048, LKV = 2048, D = 512, H = 512;
    const float scale = 1.0f / sqrtf((float)H);

    char* p = (char*)d_ws;
    u16* Xt   = (u16*)p; p += (size_t)Bn * D * LKV * 2;   // 32MB; reused as qbf
    u16* G    = (u16*)p; p += (size_t)Bn * D * D * 2;     // 8MB; reused as Ft
    u16* T2   = (u16*)p; p += (size_t)Bn * H * D * 2;     // 8MB
    u16* P    = (u16*)p; p += (size_t)D * H * 2;
    u16* WqT  = (u16*)p; p += (size_t)D * H * 2;
    u16* WkT  = (u16*)p; p += (size_t)D * H * 2;
    u16* Wvb  = (u16*)p; p += (size_t)H * D * 2;
    float* partials = (float*)p; p += (size_t)Bn * 32 * D * 4;  // 1MB
    float* u    = (float*)p; p += (size_t)Bn * H * 4;
    float* w    = (float*)p; p += (size_t)Bn * H * 4;
    float* bvec = (float*)p; p += (size_t)Bn * D * 4;
    float* vqu  = (float*)p; p += (size_t)Bn * D * 4;
    float* f0   = (float*)p; p += (size_t)Bn * H * 4;
    float* a    = (float*)p; p += (size_t)D * 4;
    float* vqk  = (float*)p; p += (size_t)D * 4;
    float* flag = (float*)p; p += 4 * 4;
    u16* qbf = Xt;
    u16* Ft  = G;

    // 1) bias flag + zero f0
    bias_flag_f0<<<dim3(1), dim3(512), 0, stream>>>(bq, bk, bv, flag, f0);

    // 2) X -> Xt (bf16, transposed) + column-sum partials
    transpose_x_colsum<<<dim3(D / 64, LKV / 64, Bn), dim3(256), 0, stream>>>(
        x, Xt, partials);

    // 3) weights -> WqT, WkT, Wvb
    weights_prep<<<dim3(8, 8, 3), dim3(256), 0, stream>>>(Wq, Wk, Wv, WqT, WkT, Wvb);

    // 4) P = scale * Wq^T Wk
    gemm_bt<true><<<dim3(4, 4, 1), dim3(256), 0, stream>>>(
        WqT, WkT, P, D, H, H, 0L, 0L, 0L, scale, nullptr, 0L);

    // 5) bias vectors stage 1 (early-exit when flag==0)
    bias_pre<<<dim3(2, Bn), dim3(512), 0, stream>>>(flag, partials, Wk, Wv, Wq, bq, bk,
                                                    u, w, a, vqk);

    // 6) G = Xt Xt^T  (K=2048)
    gemm_bt<true><<<dim3(4, 4, Bn), dim3(256), 0, stream>>>(
        Xt, Xt, G, D, D, LKV,
        (long)D * LKV, (long)D * LKV, (long)D * D, 1.0f, nullptr, 0L);

    // 7) q -> bf16 (Xt slot dead after G)
    convert_bf16_kernel<<<dim3((int)(((long)Bn * LQ * D / 4 + 255) / 256)), dim3(256),
                          0, stream>>>(q, qbf, (long)Bn * LQ * D / 4);

    // 8) bvec = G a (early-exit)
    bias_mid<<<dim3(Bn), dim3(512), 0, stream>>>(flag, G, a, bvec);

    // 9) T2 = Wv G
    gemm_bt<true><<<dim3(4, 4, Bn), dim3(256), 0, stream>>>(
        Wvb, G, T2, H, D, D,
        0L, (long)D * D, (long)H * D, 1.0f, nullptr, 0L);

    // 10) bias vectors stage 2 (early-exit)
    bias_post<<<dim3(Bn), dim3(512), 0, stream>>>(flag, Wq, Wv, u, w, bvec, bq, bk, bv,
                                                  vqu, f0, scale, (float)LKV);

    // 11) Ft = T2 P^T  (overwrites G slot; G last read in step 9)
    gemm_bt<true><<<dim3(4, 4, Bn), dim3(256), 0, stream>>>(
        T2, P, Ft, H, D, H,
        (long)H * D, 0L, (long)H * D, 1.0f, nullptr, 0L);

    // 12) rank-1 bias fixup on Ft (early-exit)
    rank1F<<<dim3(1024, Bn), dim3(256), 0, stream>>>(flag, Ft, bv, vqu, w, vqk,
                                                     scale, (float)LKV);

    // 13) ctx = q F + 1 f0^T
    gemm_bt<false><<<dim3(4, 16, Bn), dim3(256), 0, stream>>>(
        qbf, Ft, out, LQ, H, D,
        (long)LQ * D, (long)H * D, (long)LQ * H, 1.0f, f0, (long)H);
}

// Round 5
// 165.807 us; speedup vs baseline: 11.3814x; 1.1280x over previous
//
#include <hip/hip_runtime.h>
#include <math.h>

// B=16, LQ=LKV=2048, D=H=512, fp32 in/out. No softmax -> reassociate:
//   G_b = X_b^T X_b            [512,512] (K=2048, symmetric)
//   P   = scale * Wq^T Wk      [512,512] (batch-independent)
//   T2_b= Wv G_b ;  Ft_b = T2_b P^T  (= F^T)
//   ctx = q F + 1 f0^T         (f0 + rank-1 terms exact, flag-guarded; 0 here)
// GEMMs: C[M,N]=alpha*A[M,K]*B[N,K]^T, bf16 K-contig, 128x128 tile, 4 waves,
// 2-phase double-buffered LDS (stage t+1 overlaps MFMA of t, ONE barrier/K-step).

typedef unsigned short u16;
typedef __attribute__((ext_vector_type(8))) short bf16x8;
typedef __attribute__((ext_vector_type(4))) float f32x4;

__device__ __forceinline__ u16 f2bf(float f) {
    union { float f; unsigned u; } a; a.f = f;
    unsigned r = a.u + 0x7FFFu + ((a.u >> 16) & 1u);
    return (u16)(r >> 16);
}
__device__ __forceinline__ float bf2f(u16 h) {
    union { unsigned u; float f; } a; a.u = ((unsigned)h) << 16;
    return a.f;
}

// ---------------- dbuf MFMA GEMM (bf16 A,B) --------------------------------
template<bool OUT_BF16>
__global__ __launch_bounds__(256) void gemm_bt(
    const u16* __restrict__ A, const u16* __restrict__ B, void* __restrict__ Cv,
    int M, int N, int K,
    long sA_b, long sB_b, long sC_b,
    float alpha, const float* __restrict__ rowbias, long sRB_b)
{
    __shared__ u16 As[2][4096];
    __shared__ u16 Bs[2][4096];
    const int b = blockIdx.z;
    const u16* Ab = A + (long)b * sA_b;
    const u16* Bb = B + (long)b * sB_b;
    const int i0 = blockIdx.y * 128, j0 = blockIdx.x * 128;
    const int t = threadIdx.x, wv = t >> 6, ln = t & 63;
    const int lr = ln & 15, lk = (ln >> 4) * 8;
    const int wrow = (wv >> 1) * 64, wcol = (wv & 1) * 64;

    f32x4 acc[4][4];
#pragma unroll
    for (int m = 0; m < 4; ++m)
#pragma unroll
        for (int n = 0; n < 4; ++n) acc[m][n] = (f32x4){0.f, 0.f, 0.f, 0.f};

    const int nt = K >> 5;
    auto stage = [&](int buf, int k0) {
#pragma unroll
        for (int e = 0; e < 2; ++e) {
            const int byteoff = (t + 256 * e) * 16;
            const int row = byteoff >> 6;
            const int cole = (byteoff & 63) >> 1;
            __builtin_amdgcn_global_load_lds(
                (const __attribute__((address_space(1))) unsigned*)
                    (Ab + (long)(i0 + row) * K + (k0 + cole)),
                (__attribute__((address_space(3))) unsigned*)&As[buf][e * 2048 + wv * 512],
                16, 0, 0);
            __builtin_amdgcn_global_load_lds(
                (const __attribute__((address_space(1))) unsigned*)
                    (Bb + (long)(j0 + row) * K + (k0 + cole)),
                (__attribute__((address_space(3))) unsigned*)&Bs[buf][e * 2048 + wv * 512],
                16, 0, 0);
        }
    };

    stage(0, 0);
    __syncthreads();
    for (int it = 0; it < nt; ++it) {
        const int c = it & 1;
        if (it + 1 < nt) stage(c ^ 1, (it + 1) * 32);
        bf16x8 af[4], bfr[4];
#pragma unroll
        for (int m = 0; m < 4; ++m)
            af[m] = *(const bf16x8*)&As[c][(wrow + m * 16 + lr) * 32 + lk];
#pragma unroll
        for (int n = 0; n < 4; ++n)
            bfr[n] = *(const bf16x8*)&Bs[c][(wcol + n * 16 + lr) * 32 + lk];
#pragma unroll
        for (int m = 0; m < 4; ++m)
#pragma unroll
            for (int n = 0; n < 4; ++n)
                acc[m][n] = __builtin_amdgcn_mfma_f32_16x16x32_bf16(
                    af[m], bfr[n], acc[m][n], 0, 0, 0);
        __syncthreads();
    }

    const int rbase = (ln >> 4) * 4;
    if (OUT_BF16) {
        u16* C = (u16*)Cv + (long)b * sC_b;
#pragma unroll
        for (int m = 0; m < 4; ++m)
#pragma unroll
            for (int n = 0; n < 4; ++n) {
                const int col = j0 + wcol + n * 16 + lr;
#pragma unroll
                for (int r = 0; r < 4; ++r) {
                    const int rowi = i0 + wrow + m * 16 + rbase + r;
                    C[(long)rowi * N + col] = f2bf(acc[m][n][r] * alpha);
                }
            }
    } else {
        float* C = (float*)Cv + (long)b * sC_b;
#pragma unroll
        for (int m = 0; m < 4; ++m)
#pragma unroll
            for (int n = 0; n < 4; ++n) {
                const int col = j0 + wcol + n * 16 + lr;
                const float bias = rowbias ? rowbias[(long)b * sRB_b + col] : 0.0f;
#pragma unroll
                for (int r = 0; r < 4; ++r) {
                    const int rowi = i0 + wrow + m * 16 + rbase + r;
                    C[(long)rowi * N + col] = acc[m][n][r] * alpha + bias;
                }
            }
    }
}

// ---------------- ctx GEMM: A = q fp32 (reg-staged cvt), B bf16 DMA ---------
__global__ __launch_bounds__(256) void gemm_aq_f32(
    const float* __restrict__ A, const u16* __restrict__ B, float* __restrict__ C,
    int M, int N, int K,
    long sA_b, long sB_b, long sC_b,
    float alpha, const float* __restrict__ rowbias, long sRB_b)
{
    __shared__ u16 As[2][4096];
    __shared__ u16 Bs[2][4096];
    const int b = blockIdx.z;
    const float* Ab = A + (long)b * sA_b;
    const u16* Bb = B + (long)b * sB_b;
    const int i0 = blockIdx.y * 128, j0 = blockIdx.x * 128;
    const int t = threadIdx.x, wv = t >> 6, ln = t & 63;
    const int lr = ln & 15, lk = (ln >> 4) * 8;
    const int wrow = (wv >> 1) * 64, wcol = (wv & 1) * 64;
    const int arow = t >> 1, acol = (t & 1) * 16;   // A-tile: 16 elems/thread

    f32x4 acc[4][4];
#pragma unroll
    for (int m = 0; m < 4; ++m)
#pragma unroll
        for (int n = 0; n < 4; ++n) acc[m][n] = (f32x4){0.f, 0.f, 0.f, 0.f};

    const int nt = K >> 5;
    float4 qv[4];
    auto loadq = [&](int k0) {
        const float4* ga = (const float4*)(Ab + (long)(i0 + arow) * K + k0 + acol);
#pragma unroll
        for (int e = 0; e < 4; ++e) qv[e] = ga[e];
    };
    auto stageB = [&](int buf, int k0) {
#pragma unroll
        for (int e = 0; e < 2; ++e) {
            const int byteoff = (t + 256 * e) * 16;
            const int row = byteoff >> 6;
            const int cole = (byteoff & 63) >> 1;
            __builtin_amdgcn_global_load_lds(
                (const __attribute__((address_space(1))) unsigned*)
                    (Bb + (long)(j0 + row) * K + (k0 + cole)),
                (__attribute__((address_space(3))) unsigned*)&Bs[buf][e * 2048 + wv * 512],
                16, 0, 0);
        }
    };
    auto writeA = [&](int buf) {
        union { u16 h[16]; bf16x8 v[2]; } r;
#pragma unroll
        for (int e = 0; e < 4; ++e) {
            r.h[4 * e + 0] = f2bf(qv[e].x); r.h[4 * e + 1] = f2bf(qv[e].y);
            r.h[4 * e + 2] = f2bf(qv[e].z); r.h[4 * e + 3] = f2bf(qv[e].w);
        }
        *(bf16x8*)&As[buf][arow * 32 + acol] = r.v[0];
        *(bf16x8*)&As[buf][arow * 32 + acol + 8] = r.v[1];
    };

    loadq(0); stageB(0, 0); writeA(0);
    __syncthreads();
    for (int it = 0; it < nt; ++it) {
        const int c = it & 1;
        if (it + 1 < nt) { loadq((it + 1) * 32); stageB(c ^ 1, (it + 1) * 32); }
        bf16x8 af[4], bfr[4];
#pragma unroll
        for (int m = 0; m < 4; ++m)
            af[m] = *(const bf16x8*)&As[c][(wrow + m * 16 + lr) * 32 + lk];
#pragma unroll
        for (int n = 0; n < 4; ++n)
            bfr[n] = *(const bf16x8*)&Bs[c][(wcol + n * 16 + lr) * 32 + lk];
#pragma unroll
        for (int m = 0; m < 4; ++m)
#pragma unroll
            for (int n = 0; n < 4; ++n)
                acc[m][n] = __builtin_amdgcn_mfma_f32_16x16x32_bf16(
                    af[m], bfr[n], acc[m][n], 0, 0, 0);
        if (it + 1 < nt) writeA(c ^ 1);
        __syncthreads();
    }

    const int rbase = (ln >> 4) * 4;
    float* Cb = C + (long)b * sC_b;
#pragma unroll
    for (int m = 0; m < 4; ++m)
#pragma unroll
        for (int n = 0; n < 4; ++n) {
            const int col = j0 + wcol + n * 16 + lr;
            const float bias = rowbias ? rowbias[(long)b * sRB_b + col] : 0.0f;
#pragma unroll
            for (int r = 0; r < 4; ++r) {
                const int rowi = i0 + wrow + m * 16 + rbase + r;
                Cb[(long)rowi * N + col] = acc[m][n][r] * alpha + bias;
            }
        }
}

// ---------------- x: transpose+convert+fused column partial sums ------------
__global__ __launch_bounds__(256) void transpose_x_colsum(
    const float* __restrict__ in, u16* __restrict__ outp, float* __restrict__ partials)
{
    __shared__ float tile[64][65];
    __shared__ float cp[4][64];
    const int R = 2048, C = 512;
    int b = blockIdx.z;
    int r0 = blockIdx.y * 64, c0 = blockIdx.x * 64;
    const float* ib = in + (long)b * R * C;
    u16* ob = outp + (long)b * R * C;
    int t = threadIdx.x, cc = t & 63, rr = t >> 6;
    float acc = 0.f;
#pragma unroll
    for (int i = 0; i < 16; ++i) {
        float v = ib[(long)(r0 + rr + 4 * i) * C + c0 + cc];
        tile[rr + 4 * i][cc] = v;
        acc += v;
    }
    cp[rr][cc] = acc;
    __syncthreads();
#pragma unroll
    for (int i = 0; i < 16; ++i)
        ob[(long)(c0 + rr + 4 * i) * R + r0 + cc] = f2bf(tile[cc][rr + 4 * i]);
    if (rr == 0)
        partials[((long)b * 32 + blockIdx.y) * 512 + c0 + cc] =
            cp[0][cc] + cp[1][cc] + cp[2][cc] + cp[3][cc];
}

// ---------------- weights: WqT, WkT (transpose), Wvb (straight) -------------
__global__ __launch_bounds__(256) void weights_prep(
    const float* __restrict__ Wq, const float* __restrict__ Wk, const float* __restrict__ Wv,
    u16* __restrict__ WqT, u16* __restrict__ WkT, u16* __restrict__ Wvb)
{
    __shared__ float tile[64][65];
    const int N = 512;
    int z = blockIdx.z;
    int r0 = blockIdx.y * 64, c0 = blockIdx.x * 64;
    const float* ib = z == 0 ? Wq : (z == 1 ? Wk : Wv);
    u16* ob = z == 0 ? WqT : (z == 1 ? WkT : Wvb);
    int t = threadIdx.x, cc = t & 63, rr = t >> 6;
    if (z == 2) {
#pragma unroll
        for (int i = 0; i < 16; ++i) {
            long o = (long)(r0 + rr + 4 * i) * N + c0 + cc;
            ob[o] = f2bf(ib[o]);
        }
        return;
    }
#pragma unroll
    for (int i = 0; i < 16; ++i)
        tile[rr + 4 * i][cc] = ib[(long)(r0 + rr + 4 * i) * N + c0 + cc];
    __syncthreads();
#pragma unroll
    for (int i = 0; i < 16; ++i)
        ob[(long)(c0 + rr + 4 * i) * N + r0 + cc] = f2bf(tile[cc][rr + 4 * i]);
}

// ---------------- bias flag + f0 zero (1 block, 512 thr) --------------------
__global__ __launch_bounds__(512) void bias_flag_f0(
    const float* __restrict__ bq, const float* __restrict__ bk,
    const float* __restrict__ bv, float* __restrict__ flag, float* __restrict__ f0)
{
    __shared__ float red[8];
    int t = threadIdx.x;
    float m = fabsf(bq[t]);
    m = fmaxf(m, fabsf(bk[t]));
    m = fmaxf(m, fabsf(bv[t]));
#pragma unroll
    for (int s = 1; s < 64; s <<= 1) m = fmaxf(m, __shfl_xor(m, s, 64));
    if ((t & 63) == 0) red[t >> 6] = m;
    __syncthreads();
    if (t == 0) {
        float mm = red[0];
#pragma unroll
        for (int i = 1; i < 8; ++i) mm = fmaxf(mm, red[i]);
        flag[0] = mm;
    }
#pragma unroll
    for (int i = 0; i < 16; ++i) f0[t + 512 * i] = 0.0f;
}

// ---------------- merged bias chain (exact; early-exit when flag==0) --------
__global__ __launch_bounds__(512) void bias_all(
    const float* __restrict__ flag, const float* __restrict__ partials,
    const float* __restrict__ Wq, const float* __restrict__ Wk, const float* __restrict__ Wv,
    const float* __restrict__ bq, const float* __restrict__ bk, const float* __restrict__ bv,
    const u16* __restrict__ G,
    float* __restrict__ w_out, float* __restrict__ vqu, float* __restrict__ vqk,
    float* __restrict__ f0, float scale, float Lf)
{
    if (flag[0] == 0.0f) return;
    __shared__ float s_sh[512], a_sh[512], u_sh[512], b_sh[512], w_sh[512];
    int b = blockIdx.x, t = threadIdx.x;
    int wv_ = t >> 6, ln = t & 63;
    // s = colsum(X_b); a = Wk^T bq; vqk = Wq^T bk
    float acc = 0.f;
    for (int j = 0; j < 32; ++j) acc += partials[((long)b * 32 + j) * 512 + t];
    s_sh[t] = acc;
    float pa = 0.f, pv = 0.f;
    for (int h = 0; h < 512; ++h) {
        pa += bq[h] * Wk[(long)h * 512 + t];
        pv += Wq[(long)h * 512 + t] * bk[h];
    }
    a_sh[t] = pa;
    if (b == 0) vqk[t] = pv;
    __syncthreads();
    // u = Wk s ; w = Wv s  (row dots, wave-shuffle)
    for (int hh = 0; hh < 64; ++hh) {
        int h = wv_ * 64 + hh;
        float pu = 0.f, pw = 0.f;
#pragma unroll
        for (int c = 0; c < 8; ++c) {
            float sv = s_sh[ln + 64 * c];
            pu += Wk[(long)h * 512 + ln + 64 * c] * sv;
            pw += Wv[(long)h * 512 + ln + 64 * c] * sv;
        }
#pragma unroll
        for (int m = 1; m < 64; m <<= 1) { pu += __shfl_xor(pu, m, 64); pw += __shfl_xor(pw, m, 64); }
        if (ln == 0) { u_sh[h] = pu; w_sh[h] = pw; }
    }
    __syncthreads();
    w_out[(long)b * 512 + t] = w_sh[t];
    // bvec = G a (G symmetric -> coalesced); vqu = Wq^T u; d1,d2
    float bb = 0.f;
    for (int j = 0; j < 512; ++j) bb += a_sh[j] * bf2f(G[(long)b * 262144 + (long)j * 512 + t]);
    b_sh[t] = bb;
    float pvq = 0.f, d1 = 0.f, d2 = 0.f;
    for (int h = 0; h < 512; ++h) {
        pvq += Wq[(long)h * 512 + t] * u_sh[h];
        d1 += bq[h] * u_sh[h];
        d2 += bq[h] * bk[h];
    }
    vqu[(long)b * 512 + t] = pvq;
    __syncthreads();
    // f0[hp] = scale*(Wv[hp,:]·bvec + d1 bv + d2 w + L d2 bv)
    for (int hh = 0; hh < 64; ++hh) {
        int hp = wv_ * 64 + hh;
        float p = 0.f;
#pragma unroll
        for (int c = 0; c < 8; ++c) p += Wv[(long)hp * 512 + ln + 64 * c] * b_sh[ln + 64 * c];
#pragma unroll
        for (int m = 1; m < 64; m <<= 1) p += __shfl_xor(p, m, 64);
        if (ln == 0)
            f0[(long)b * 512 + hp] =
                scale * (p + d1 * bv[hp] + d2 * w_sh[hp] + Lf * d2 * bv[hp]);
    }
}

__global__ void rank1F(const float* __restrict__ flag,
                       u16* __restrict__ Ft, const float* __restrict__ bv,
                       const float* __restrict__ vqu, const float* __restrict__ w,
                       const float* __restrict__ vqk, float scale, float Lf)
{
    if (flag[0] == 0.0f) return;
    int b = blockIdx.y;
    long base = (long)blockIdx.x * 256 + threadIdx.x;
    for (int e = 0; e < 16; ++e) {
        long idx = base + (long)e * 16384;
        int hp = (int)(idx >> 9), d = (int)(idx & 511);
        float add = scale * (bv[hp] * vqu[(long)b * 512 + d] + w[(long)b * 512 + hp] * vqk[d]
                             + Lf * bv[hp] * vqk[d]);
        if (add != 0.f) {
            long o = (long)b * 262144 + idx;
            Ft[o] = f2bf(bf2f(Ft[o]) + add);
        }
    }
}

// ---------------- launch --------------------------------------------------
extern "C" void kernel_launch(void* const* d_in, const int* in_sizes, int n_in,
                              void* d_out, int out_size, void* d_ws, size_t ws_size,
                              hipStream_t stream) {
    const float* q  = (const float*)d_in[0];
    const float* x  = (const float*)d_in[1];
    const float* Wq = (const float*)d_in[2];
    const float* bq = (const float*)d_in[3];
    const float* Wk = (const float*)d_in[4];
    const float* bk = (const float*)d_in[5];
    const float* Wv = (const float*)d_in[6];
    const float* bv = (const float*)d_in[7];
    float* out = (float*)d_out;

    const int Bn = 16, LQ = 2048, LKV = 2048, D = 512, H = 512;
    const float scale = 1.0f / sqrtf((float)H);

    char* p = (char*)d_ws;
    u16* Xt   = (u16*)p; p += (size_t)Bn * D * LKV * 2;   // 32MB (dead after G)
    u16* G    = (u16*)p; p += (size_t)Bn * D * D * 2;     // 8MB; reused as Ft
    u16* T2   = (u16*)p; p += (size_t)Bn * H * D * 2;     // 8MB
    u16* P    = (u16*)p; p += (size_t)D * H * 2;
    u16* WqT  = (u16*)p; p += (size_t)D * H * 2;
    u16* WkT  = (u16*)p; p += (size_t)D * H * 2;
    u16* Wvb  = (u16*)p; p += (size_t)H * D * 2;
    float* partials = (float*)p; p += (size_t)Bn * 32 * D * 4;  // 1MB
    float* w    = (float*)p; p += (size_t)Bn * H * 4;
    float* vqu  = (float*)p; p += (size_t)Bn * D * 4;
    float* f0   = (float*)p; p += (size_t)Bn * H * 4;
    float* vqk  = (float*)p; p += (size_t)D * 4;
    float* flag = (float*)p; p += 4 * 4;
    u16* Ft = G;

    // 1) bias flag + zero f0
    bias_flag_f0<<<dim3(1), dim3(512), 0, stream>>>(bq, bk, bv, flag, f0);

    // 2) X -> Xt (bf16, transposed) + column-sum partials
    transpose_x_colsum<<<dim3(D / 64, LKV / 64, Bn), dim3(256), 0, stream>>>(
        x, Xt, partials);

    // 3) weights -> WqT, WkT, Wvb
    weights_prep<<<dim3(8, 8, 3), dim3(256), 0, stream>>>(Wq, Wk, Wv, WqT, WkT, Wvb);

    // 4) P = scale * Wq^T Wk
    gemm_bt<true><<<dim3(4, 4, 1), dim3(256), 0, stream>>>(
        WqT, WkT, P, D, H, H, 0L, 0L, 0L, scale, nullptr, 0L);

    // 5) G = Xt Xt^T  (K=2048)
    gemm_bt<true><<<dim3(4, 4, Bn), dim3(256), 0, stream>>>(
        Xt, Xt, G, D, D, LKV,
        (long)D * LKV, (long)D * LKV, (long)D * D, 1.0f, nullptr, 0L);

    // 6) merged bias chain (early-exit when flag==0)
    bias_all<<<dim3(Bn), dim3(512), 0, stream>>>(flag, partials, Wq, Wk, Wv,
                                                 bq, bk, bv, G, w, vqu, vqk, f0,
                                                 scale, (float)LKV);

    // 7) T2 = Wv G
    gemm_bt<true><<<dim3(4, 4, Bn), dim3(256), 0, stream>>>(
        Wvb, G, T2, H, D, D,
        0L, (long)D * D, (long)H * D, 1.0f, nullptr, 0L);

    // 8) Ft = T2 P^T  (overwrites G slot; G last read in step 7)
    gemm_bt<true><<<dim3(4, 4, Bn), dim3(256), 0, stream>>>(
        T2, P, Ft, H, D, H,
        (long)H * D, 0L, (long)H * D, 1.0f, nullptr, 0L);

    // 9) rank-1 bias fixup on Ft (early-exit)
    rank1F<<<dim3(64, Bn), dim3(256), 0, stream>>>(flag, Ft, bv, vqu, w, vqk,
                                                   scale, (float)LKV);

    // 10) ctx = q F + 1 f0^T  (q fp32 converted in-kernel)
    gemm_aq_f32<<<dim3(4, 16, Bn), dim3(256), 0, stream>>>(
        q, Ft, out, LQ, H, D,
        (long)LQ * D, (long)H * D, (long)LQ * H, 1.0f, f0, (long)H);
}

// Round 6
// 154.490 us; speedup vs baseline: 12.2151x; 1.0733x over previous
//
#include <hip/hip_runtime.h>
#include <math.h>

// B=16, LQ=LKV=2048, D=H=512, fp32 in/out. No softmax -> reassociate:
//   G_b = X_b^T X_b            [512,512] (K=2048, symmetric)
//   P   = scale * Wq^T Wk      [512,512] (batch-independent)
//   T2_b= Wv G_b ;  Ft_b = T2_b P^T  (= F^T)
//   ctx = q F + 1 f0^T         (bias terms exact, flag-guarded; 0 here)
// GEMM: C[M,N]=alpha*A[M,K]*B[N,K]^T, 128x128 tile, 4 waves, 16x16x32 bf16 MFMA.
//  - LDS chunk swizzle: byte ^= ((row>>1)&3)<<4 (pre-swizzled gload_lds source)
//  - 3 LDS buffers, prefetch depth 2, raw s_barrier + counted vmcnt (never 0)
//  - bijective XCD swizzle, j-fastest decode (q/G panel sharers on same L2)
//  - optional fused fp32->bf16 A-path (ctx), 1-iter lookahead, write-late

typedef unsigned short u16;
typedef __attribute__((ext_vector_type(8))) short bf16x8;
typedef __attribute__((ext_vector_type(4))) float f32x4;

__device__ __forceinline__ u16 f2bf(float f) {
    union { float f; unsigned u; } a; a.f = f;
    unsigned r = a.u + 0x7FFFu + ((a.u >> 16) & 1u);
    return (u16)(r >> 16);
}
__device__ __forceinline__ float bf2f(u16 h) {
    union { unsigned u; float f; } a; a.u = ((unsigned)h) << 16;
    return a.f;
}

// ---------------- MFMA GEMM template ---------------------------------------
template<bool A_F32, bool OUT_BF16>
__global__ __launch_bounds__(256) void gemm_k(
    const void* __restrict__ Av, const u16* __restrict__ B, void* __restrict__ Cv,
    int N, int K,
    long sA_b, long sB_b, long sC_b,
    float alpha, const float* __restrict__ rowbias, long sRB_b)
{
    __shared__ u16 As[3][4096];
    __shared__ u16 Bs[3][4096];

    // bijective XCD swizzle (all launches have nwg % 8 == 0), j fastest
    const int gx = gridDim.x, gy = gridDim.y;
    const int nwg = gx * gy * (int)gridDim.z;
    const int flat = blockIdx.x + gx * (blockIdx.y + gy * blockIdx.z);
    const int nf = (flat & 7) * (nwg >> 3) + (flat >> 3);
    const int jb = nf % gx;
    const int t1 = nf / gx;
    const int ib = t1 % gy;
    const int b  = t1 / gy;
    const int i0 = ib * 128, j0 = jb * 128;

    const u16* Bb = B + (long)b * sB_b;
    const u16* Ab = A_F32 ? nullptr : ((const u16*)Av + (long)b * sA_b);
    const float* Af = A_F32 ? ((const float*)Av + (long)b * sA_b) : nullptr;

    const int t = threadIdx.x, wv = t >> 6, ln = t & 63;
    const int lr = ln & 15, lkb = ((ln >> 4) * 8) * 2;   // frag k-chunk byte
    const int wrow = (wv >> 1) * 64, wcol = (wv & 1) * 64;

    f32x4 acc[4][4];
#pragma unroll
    for (int m = 0; m < 4; ++m)
#pragma unroll
        for (int n = 0; n < 4; ++n) acc[m][n] = (f32x4){0.f, 0.f, 0.f, 0.f};

    const int nt = K >> 5;

    // staging: LDS linear per-lane; SOURCE pre-swizzled (chunk ^ key(row))
    auto stageB = [&](int buf, int k0) {
#pragma unroll
        for (int e = 0; e < 2; ++e) {
            const int o = e * 4096 + wv * 1024 + ln * 16;      // lds byte (this lane)
            const int row = o >> 6;
            const int sw = (o & 63) ^ (((row >> 1) & 3) << 4);
            __builtin_amdgcn_global_load_lds(
                (const __attribute__((address_space(1))) unsigned*)
                    (Bb + (long)(j0 + row) * K + (k0 + (sw >> 1))),
                (__attribute__((address_space(3))) unsigned*)&Bs[buf][e * 2048 + wv * 512],
                16, 0, 0);
        }
    };
    auto stageA = [&](int buf, int k0) {
#pragma unroll
        for (int e = 0; e < 2; ++e) {
            const int o = e * 4096 + wv * 1024 + ln * 16;
            const int row = o >> 6;
            const int sw = (o & 63) ^ (((row >> 1) & 3) << 4);
            __builtin_amdgcn_global_load_lds(
                (const __attribute__((address_space(1))) unsigned*)
                    (Ab + (long)(i0 + row) * K + (k0 + (sw >> 1))),
                (__attribute__((address_space(3))) unsigned*)&As[buf][e * 2048 + wv * 512],
                16, 0, 0);
        }
    };

    auto ldfrag = [&](int c, bf16x8 (&af)[4], bf16x8 (&bfr)[4]) {
#pragma unroll
        for (int m = 0; m < 4; ++m) {
            const int row = wrow + m * 16 + lr;
            af[m] = *(const bf16x8*)
                &As[c][row * 32 + ((lkb ^ (((row >> 1) & 3) << 4)) >> 1)];
        }
#pragma unroll
        for (int n = 0; n < 4; ++n) {
            const int row = wcol + n * 16 + lr;
            bfr[n] = *(const bf16x8*)
                &Bs[c][row * 32 + ((lkb ^ (((row >> 1) & 3) << 4)) >> 1)];
        }
    };

    // fused-A helpers (q fp32 -> bf16): thread owns 16 elems of one row
    const int arow = t >> 1;
    const int acb = (t & 1) * 32;                     // chunk byte base (bf16)
    const int akey = ((arow >> 1) & 3) << 4;
    auto loadq = [&](float4 (&qv)[4], int k0) {
        const float4* ga = (const float4*)(Af + (long)(i0 + arow) * K + k0 + (acb >> 1));
#pragma unroll
        for (int e = 0; e < 4; ++e) qv[e] = ga[e];
    };
    auto writeA = [&](int buf, const float4 (&qv)[4]) {
        union { u16 h[16]; bf16x8 v2[2]; } r;
#pragma unroll
        for (int e = 0; e < 4; ++e) {
            r.h[4 * e + 0] = f2bf(qv[e].x); r.h[4 * e + 1] = f2bf(qv[e].y);
            r.h[4 * e + 2] = f2bf(qv[e].z); r.h[4 * e + 3] = f2bf(qv[e].w);
        }
        *(bf16x8*)&As[buf][arow * 32 + ((acb ^ akey) >> 1)]        = r.v2[0];
        *(bf16x8*)&As[buf][arow * 32 + (((acb + 16) ^ akey) >> 1)] = r.v2[1];
    };

#define MFMAS                                                                 \
    do {                                                                      \
        __builtin_amdgcn_s_setprio(1);                                        \
        _Pragma("unroll")                                                     \
        for (int m = 0; m < 4; ++m)                                           \
            _Pragma("unroll")                                                 \
            for (int n = 0; n < 4; ++n)                                       \
                acc[m][n] = __builtin_amdgcn_mfma_f32_16x16x32_bf16(          \
                    af[m], bfr[n], acc[m][n], 0, 0, 0);                       \
        __builtin_amdgcn_s_setprio(0);                                        \
    } while (0)

    if constexpr (!A_F32) {
        stageA(0, 0); stageB(0, 0); stageA(1, 32); stageB(1, 32);
        asm volatile("s_waitcnt vmcnt(4)" ::: "memory");   // tile0 done
        __builtin_amdgcn_s_barrier();
        int c = 0;
        for (int it = 0; it < nt; ++it) {
            const int nb = c + 2 >= 3 ? c - 1 : c + 2;
            const bool pf = (it + 2) < nt;
            if (pf) { stageA(nb, (it + 2) * 32); stageB(nb, (it + 2) * 32); }
            bf16x8 af[4], bfr[4];
            ldfrag(c, af, bfr);
            MFMAS;
            if (pf) asm volatile("s_waitcnt vmcnt(4)" ::: "memory");  // tile it+1 done
            else    asm volatile("s_waitcnt vmcnt(0)" ::: "memory");
            __builtin_amdgcn_s_barrier();
            c = c + 1 >= 3 ? 0 : c + 1;
        }
    } else {
        // nt even (K=512). 1-iter q lookahead, static ping-pong reg sets.
        float4 qA[4], qB[4];
        stageB(0, 0); stageB(1, 32);
        loadq(qA, 0); loadq(qB, 32);
        asm volatile("s_waitcnt vmcnt(0)" ::: "memory");
        writeA(0, qA);
        asm volatile("s_waitcnt lgkmcnt(0)" ::: "memory");
        __builtin_amdgcn_s_barrier();
        int c = 0;
#define CTX_PHASE(QLOAD, QWRITE)                                              \
        {                                                                     \
            const int wb = c + 1 >= 3 ? c - 2 : c + 1;                        \
            const int nb = c + 2 >= 3 ? c - 1 : c + 2;                        \
            const bool pf = (it2 + 2) < nt;                                   \
            if (pf) { stageB(nb, (it2 + 2) * 32); loadq(QLOAD, (it2 + 2) * 32); } \
            bf16x8 af[4], bfr[4];                                             \
            ldfrag(c, af, bfr);                                               \
            MFMAS;                                                            \
            if (it2 + 1 < nt) {                                               \
                if (pf) asm volatile("s_waitcnt vmcnt(6)" ::: "memory");      \
                else    asm volatile("s_waitcnt vmcnt(0)" ::: "memory");      \
                writeA(wb, QWRITE);                                           \
            } else {                                                          \
                asm volatile("s_waitcnt vmcnt(0)" ::: "memory");              \
            }                                                                 \
            asm volatile("s_waitcnt lgkmcnt(0)" ::: "memory");                \
            __builtin_amdgcn_s_barrier();                                     \
            c = wb;                                                           \
            ++it2;                                                            \
        }
        int it2 = 0;
        while (it2 < nt) {
            CTX_PHASE(qA, qB)   // even it: load tile it+2 -> qA, write tile it+1 from qB
            CTX_PHASE(qB, qA)   // odd  it
        }
#undef CTX_PHASE
    }
#undef MFMAS

    const int rbase = (ln >> 4) * 4;
    if (OUT_BF16) {
        u16* C = (u16*)Cv + (long)b * sC_b;
#pragma unroll
        for (int m = 0; m < 4; ++m)
#pragma unroll
            for (int n = 0; n < 4; ++n) {
                const int col = j0 + wcol + n * 16 + lr;
#pragma unroll
                for (int r = 0; r < 4; ++r) {
                    const int rowi = i0 + wrow + m * 16 + rbase + r;
                    C[(long)rowi * N + col] = f2bf(acc[m][n][r] * alpha);
                }
            }
    } else {
        float* C = (float*)Cv + (long)b * sC_b;
#pragma unroll
        for (int m = 0; m < 4; ++m)
#pragma unroll
            for (int n = 0; n < 4; ++n) {
                const int col = j0 + wcol + n * 16 + lr;
                const float bias = rowbias ? rowbias[(long)b * sRB_b + col] : 0.0f;
#pragma unroll
                for (int r = 0; r < 4; ++r) {
                    const int rowi = i0 + wrow + m * 16 + rbase + r;
                    C[(long)rowi * N + col] = acc[m][n][r] * alpha + bias;
                }
            }
    }
}

// ---------------- x: transpose+convert+fused column partial sums ------------
__global__ __launch_bounds__(256) void transpose_x_colsum(
    const float* __restrict__ in, u16* __restrict__ outp, float* __restrict__ partials)
{
    __shared__ float tile[64][65];
    __shared__ float cp[4][64];
    const int R = 2048, C = 512;
    int b = blockIdx.z;
    int r0 = blockIdx.y * 64, c0 = blockIdx.x * 64;
    const float* ib = in + (long)b * R * C;
    u16* ob = outp + (long)b * R * C;
    int t = threadIdx.x, cc = t & 63, rr = t >> 6;
    float acc = 0.f;
#pragma unroll
    for (int i = 0; i < 16; ++i) {
        float v = ib[(long)(r0 + rr + 4 * i) * C + c0 + cc];
        tile[rr + 4 * i][cc] = v;
        acc += v;
    }
    cp[rr][cc] = acc;
    __syncthreads();
#pragma unroll
    for (int i = 0; i < 16; ++i)
        ob[(long)(c0 + rr + 4 * i) * R + r0 + cc] = f2bf(tile[cc][rr + 4 * i]);
    if (rr == 0)
        partials[((long)b * 32 + blockIdx.y) * 512 + c0 + cc] =
            cp[0][cc] + cp[1][cc] + cp[2][cc] + cp[3][cc];
}

// ---------------- weights: WqT, WkT (transpose), Wvb (straight) -------------
__global__ __launch_bounds__(256) void weights_prep(
    const float* __restrict__ Wq, const float* __restrict__ Wk, const float* __restrict__ Wv,
    u16* __restrict__ WqT, u16* __restrict__ WkT, u16* __restrict__ Wvb)
{
    __shared__ float tile[64][65];
    const int N = 512;
    int z = blockIdx.z;
    int r0 = blockIdx.y * 64, c0 = blockIdx.x * 64;
    const float* ib = z == 0 ? Wq : (z == 1 ? Wk : Wv);
    u16* ob = z == 0 ? WqT : (z == 1 ? WkT : Wvb);
    int t = threadIdx.x, cc = t & 63, rr = t >> 6;
    if (z == 2) {
#pragma unroll
        for (int i = 0; i < 16; ++i) {
            long o = (long)(r0 + rr + 4 * i) * N + c0 + cc;
            ob[o] = f2bf(ib[o]);
        }
        return;
    }
#pragma unroll
    for (int i = 0; i < 16; ++i)
        tile[rr + 4 * i][cc] = ib[(long)(r0 + rr + 4 * i) * N + c0 + cc];
    __syncthreads();
#pragma unroll
    for (int i = 0; i < 16; ++i)
        ob[(long)(c0 + rr + 4 * i) * N + r0 + cc] = f2bf(tile[cc][rr + 4 * i]);
}

// ---------------- bias flag + f0 zero (1 block, 512 thr) --------------------
__global__ __launch_bounds__(512) void bias_flag_f0(
    const float* __restrict__ bq, const float* __restrict__ bk,
    const float* __restrict__ bv, float* __restrict__ flag, float* __restrict__ f0)
{
    __shared__ float red[8];
    int t = threadIdx.x;
    float m = fabsf(bq[t]);
    m = fmaxf(m, fabsf(bk[t]));
    m = fmaxf(m, fabsf(bv[t]));
#pragma unroll
    for (int s = 1; s < 64; s <<= 1) m = fmaxf(m, __shfl_xor(m, s, 64));
    if ((t & 63) == 0) red[t >> 6] = m;
    __syncthreads();
    if (t == 0) {
        float mm = red[0];
#pragma unroll
        for (int i = 1; i < 8; ++i) mm = fmaxf(mm, red[i]);
        flag[0] = mm;
    }
#pragma unroll
    for (int i = 0; i < 16; ++i) f0[t + 512 * i] = 0.0f;
}

// ---------------- merged bias chain (exact; early-exit when flag==0) --------
__global__ __launch_bounds__(512) void bias_all(
    const float* __restrict__ flag, const float* __restrict__ partials,
    const float* __restrict__ Wq, const float* __restrict__ Wk, const float* __restrict__ Wv,
    const float* __restrict__ bq, const float* __restrict__ bk, const float* __restrict__ bv,
    const u16* __restrict__ G,
    float* __restrict__ w_out, float* __restrict__ vqu, float* __restrict__ vqk,
    float* __restrict__ f0, float scale, float Lf)
{
    if (flag[0] == 0.0f) return;
    __shared__ float s_sh[512], a_sh[512], u_sh[512], b_sh[512], w_sh[512];
    int b = blockIdx.x, t = threadIdx.x;
    int wv_ = t >> 6, ln = t & 63;
    float acc = 0.f;
    for (int j = 0; j < 32; ++j) acc += partials[((long)b * 32 + j) * 512 + t];
    s_sh[t] = acc;
    float pa = 0.f, pv = 0.f;
    for (int h = 0; h < 512; ++h) {
        pa += bq[h] * Wk[(long)h * 512 + t];
        pv += Wq[(long)h * 512 + t] * bk[h];
    }
    a_sh[t] = pa;
    if (b == 0) vqk[t] = pv;
    __syncthreads();
    for (int hh = 0; hh < 64; ++hh) {
        int h = wv_ * 64 + hh;
        float pu = 0.f, pw = 0.f;
#pragma unroll
        for (int c = 0; c < 8; ++c) {
            float sv = s_sh[ln + 64 * c];
            pu += Wk[(long)h * 512 + ln + 64 * c] * sv;
            pw += Wv[(long)h * 512 + ln + 64 * c] * sv;
        }
#pragma unroll
        for (int m = 1; m < 64; m <<= 1) { pu += __shfl_xor(pu, m, 64); pw += __shfl_xor(pw, m, 64); }
        if (ln == 0) { u_sh[h] = pu; w_sh[h] = pw; }
    }
    __syncthreads();
    w_out[(long)b * 512 + t] = w_sh[t];
    float bb = 0.f;
    for (int j = 0; j < 512; ++j) bb += a_sh[j] * bf2f(G[(long)b * 262144 + (long)j * 512 + t]);
    b_sh[t] = bb;
    float pvq = 0.f, d1 = 0.f, d2 = 0.f;
    for (int h = 0; h < 512; ++h) {
        pvq += Wq[(long)h * 512 + t] * u_sh[h];
        d1 += bq[h] * u_sh[h];
        d2 += bq[h] * bk[h];
    }
    vqu[(long)b * 512 + t] = pvq;
    __syncthreads();
    for (int hh = 0; hh < 64; ++hh) {
        int hp = wv_ * 64 + hh;
        float p = 0.f;
#pragma unroll
        for (int c = 0; c < 8; ++c) p += Wv[(long)hp * 512 + ln + 64 * c] * b_sh[ln + 64 * c];
#pragma unroll
        for (int m = 1; m < 64; m <<= 1) p += __shfl_xor(p, m, 64);
        if (ln == 0)
            f0[(long)b * 512 + hp] =
                scale * (p + d1 * bv[hp] + d2 * w_sh[hp] + Lf * d2 * bv[hp]);
    }
}

__global__ void rank1F(const float* __restrict__ flag,
                       u16* __restrict__ Ft, const float* __restrict__ bv,
                       const float* __restrict__ vqu, const float* __restrict__ w,
                       const float* __restrict__ vqk, float scale, float Lf)
{
    if (flag[0] == 0.0f) return;
    int b = blockIdx.y;
    long base = (long)blockIdx.x * 256 + threadIdx.x;
    for (int e = 0; e < 16; ++e) {
        long idx = base + (long)e * 16384;
        int hp = (int)(idx >> 9), d = (int)(idx & 511);
        float add = scale * (bv[hp] * vqu[(long)b * 512 + d] + w[(long)b * 512 + hp] * vqk[d]
                             + Lf * bv[hp] * vqk[d]);
        if (add != 0.f) {
            long o = (long)b * 262144 + idx;
            Ft[o] = f2bf(bf2f(Ft[o]) + add);
        }
    }
}

// ---------------- launch --------------------------------------------------
extern "C" void kernel_launch(void* const* d_in, const int* in_sizes, int n_in,
                              void* d_out, int out_size, void* d_ws, size_t ws_size,
                              hipStream_t stream) {
    const float* q  = (const float*)d_in[0];
    const float* x  = (const float*)d_in[1];
    const float* Wq = (const float*)d_in[2];
    const float* bq = (const float*)d_in[3];
    const float* Wk = (const float*)d_in[4];
    const float* bk = (const float*)d_in[5];
    const float* Wv = (const float*)d_in[6];
    const float* bv = (const float*)d_in[7];
    float* out = (float*)d_out;

    const int Bn = 16, LQ = 2048, LKV = 2048, D = 512, H = 512;
    const float scale = 1.0f / sqrtf((float)H);

    char* p = (char*)d_ws;
    u16* Xt   = (u16*)p; p += (size_t)Bn * D * LKV * 2;   // 32MB (dead after G)
    u16* G    = (u16*)p; p += (size_t)Bn * D * D * 2;     // 8MB; reused as Ft
    u16* T2   = (u16*)p; p += (size_t)Bn * H * D * 2;     // 8MB
    u16* P    = (u16*)p; p += (size_t)D * H * 2;
    u16* WqT  = (u16*)p; p += (size_t)D * H * 2;
    u16* WkT  = (u16*)p; p += (size_t)D * H * 2;
    u16* Wvb  = (u16*)p; p += (size_t)H * D * 2;
    float* partials = (float*)p; p += (size_t)Bn * 32 * D * 4;  // 1MB
    float* w    = (float*)p; p += (size_t)Bn * H * 4;
    float* vqu  = (float*)p; p += (size_t)Bn * D * 4;
    float* f0   = (float*)p; p += (size_t)Bn * H * 4;
    float* vqk  = (float*)p; p += (size_t)D * 4;
    float* flag = (float*)p; p += 4 * 4;
    u16* Ft = G;

    // 1) bias flag + zero f0
    bias_flag_f0<<<dim3(1), dim3(512), 0, stream>>>(bq, bk, bv, flag, f0);

    // 2) X -> Xt (bf16, transposed) + column-sum partials
    transpose_x_colsum<<<dim3(D / 64, LKV / 64, Bn), dim3(256), 0, stream>>>(
        x, Xt, partials);

    // 3) weights -> WqT, WkT, Wvb
    weights_prep<<<dim3(8, 8, 3), dim3(256), 0, stream>>>(Wq, Wk, Wv, WqT, WkT, Wvb);

    // 4) P = scale * Wq^T Wk
    gemm_k<false, true><<<dim3(4, 4, 1), dim3(256), 0, stream>>>(
        WqT, WkT, P, D, H, 0L, 0L, 0L, scale, nullptr, 0L);

    // 5) G = Xt Xt^T  (K=2048)
    gemm_k<false, true><<<dim3(4, 4, Bn), dim3(256), 0, stream>>>(
        Xt, Xt, G, D, LKV,
        (long)D * LKV, (long)D * LKV, (long)D * D, 1.0f, nullptr, 0L);

    // 6) merged bias chain (early-exit when flag==0)
    bias_all<<<dim3(Bn), dim3(512), 0, stream>>>(flag, partials, Wq, Wk, Wv,
                                                 bq, bk, bv, G, w, vqu, vqk, f0,
                                                 scale, (float)LKV);

    // 7) T2 = Wv G
    gemm_k<false, true><<<dim3(4, 4, Bn), dim3(256), 0, stream>>>(
        Wvb, G, T2, D, D,
        0L, (long)D * D, (long)H * D, 1.0f, nullptr, 0L);

    // 8) Ft = T2 P^T  (overwrites G slot; G last read in step 7)
    gemm_k<false, true><<<dim3(4, 4, Bn), dim3(256), 0, stream>>>(
        T2, P, Ft, D, H,
        (long)H * D, 0L, (long)H * D, 1.0f, nullptr, 0L);

    // 9) rank-1 bias fixup on Ft (early-exit)
    rank1F<<<dim3(64, Bn), dim3(256), 0, stream>>>(flag, Ft, bv, vqu, w, vqk,
                                                   scale, (float)LKV);

    // 10) ctx = q F + 1 f0^T  (q fp32 converted in-kernel)
    gemm_k<true, false><<<dim3(4, 16, Bn), dim3(256), 0, stream>>>(
        q, Ft, out, H, D,
        (long)LQ * D, (long)H * D, (long)LQ * H, 1.0f, f0, (long)H);
}